// Round 15
// baseline (118.277 us; speedup 1.0000x reference)
//
#include <hip/hip_runtime.h>
#include <cstdint>
#include <cstddef>

#define N_SP 4096
#define C_IN 512
#define C_QK 64
#define C_V  128
#define LOG2E 1.4426950408889634f

typedef unsigned short u16;
typedef __attribute__((ext_vector_type(8))) short bf16x8;
typedef __attribute__((ext_vector_type(4))) float f32x4;
typedef __attribute__((ext_vector_type(16))) float f32x16;

__device__ __forceinline__ u16 f2bf(float f) {
    union { float f; uint32_t u; } x; x.f = f;
    const uint32_t r = x.u + 0x7fffu + ((x.u >> 16) & 1u);
    return (u16)(r >> 16);
}
__device__ __forceinline__ float bf2f(u16 b) {
    union { uint32_t u; float f; } x; x.u = ((uint32_t)b) << 16;
    return x.f;
}

// Swizzled pointer into a 128-byte-row LDS tile: byte ^= (row&7)<<4. (K0/K1/K3 only)
__device__ __forceinline__ void* swzPtr(const void* base, int row, int colByte) {
    return (char*)base + row * 128 + (colByte ^ ((row & 7) << 4));
}

// ---------------- Kw: one-shot weight conversion f32 -> bf16 ----------------
__global__ __launch_bounds__(256) void wconv_kernel(
    const float* __restrict__ Wq, const float* __restrict__ Wk,
    const float* __restrict__ Wv, const float* __restrict__ Wo,
    u16* __restrict__ Wqb, u16* __restrict__ Wkb,
    u16* __restrict__ Wvb, u16* __restrict__ Wob)
{
    const int i = (blockIdx.x << 8) + threadIdx.x;   // quad index, grid 192
    const float* src; u16* dst; int off;
    if (i < 8192)       { src = Wq; dst = Wqb; off = i; }
    else if (i < 16384) { src = Wk; dst = Wkb; off = i - 8192; }
    else if (i < 32768) { src = Wv; dst = Wvb; off = i - 16384; }
    else                { src = Wo; dst = Wob; off = i - 32768; }
    const float4 v = *(const float4*)(src + ((size_t)off << 2));
    ushort4 h;
    h.x = f2bf(v.x); h.y = f2bf(v.y); h.z = f2bf(v.z); h.w = f2bf(v.w);
    *(ushort4*)(dst + ((size_t)off << 2)) = h;
}

// ---------------- K0: transpose-convert x[b][c][n] f32 -> xb[b][n][c] bf16 ----
__global__ __launch_bounds__(256) void transpose_kernel(
    const float* __restrict__ x, u16* __restrict__ xb)
{
    __shared__ u16 ts[64 * 64];
    const int t = threadIdx.x;
    const int b  = blockIdx.x & 3;
    const int cc = (blockIdx.x >> 2) & 7;
    const int nc = blockIdx.x >> 5;
    const int c0 = cc << 6, n0 = nc << 6;
    const float* xs = x + ((size_t)(b * C_IN + c0) << 12) + n0;
    for (int u = t; u < 1024; u += 256) {
        const int c = u >> 4, nq = (u & 15) << 2;
        const float4 v = *(const float4*)(xs + ((size_t)c << 12) + nq);
        ushort4 h;
        h.x = f2bf(v.x); h.y = f2bf(v.y); h.z = f2bf(v.z); h.w = f2bf(v.w);
        *(ushort4*)((char*)ts + c * 128 + ((nq << 1) ^ (((c >> 3) & 7) << 4))) = h;
    }
    __syncthreads();
    for (int u = t; u < 512; u += 256) {
        const int n = u >> 3, cg = u & 7;
        u16 pk[8];
        #pragma unroll
        for (int j = 0; j < 8; ++j) {
            const int c = (cg << 3) + j;
            pk[j] = *(const u16*)((char*)ts + c * 128 + ((n << 1) ^ (cg << 4)));
        }
        *(ushort4*)(xb + ((size_t)((b << 12) + n0 + n) << 9) + c0 + (cg << 3)) =
            *(ushort4*)&pk[0];
        *(ushort4*)(xb + ((size_t)((b << 12) + n0 + n) << 9) + c0 + (cg << 3) + 4) =
            *(ushort4*)&pk[4];
    }
}

// ---------------- K1: fused QKV projection (xb read ONCE), bf16 MFMA ---------
// Block = (b, 64-n chunk), 4 waves: w0=Q, w1=K, w2=V[0:64), w3=V[64:128).
// Q -> Qb[b][n][64] (*log2e). K,V -> fragment-ordered Kf/Vf (see R10).
__global__ __launch_bounds__(256) void qkv_kernel(
    const u16* __restrict__ xb,
    const u16* __restrict__ Wqb, const float* __restrict__ bq,
    const u16* __restrict__ Wkb, const float* __restrict__ bk,
    const u16* __restrict__ Wvb, const float* __restrict__ bv,
    u16* __restrict__ Qb, u16* __restrict__ Kf, u16* __restrict__ Vf)
{
    __shared__ u16 wt[256 * 64];  // 32 KB: all 256 W rows x 64-c chunk
    __shared__ u16 xt[64 * 64];   // 8 KB:  xb chunk [n][64 c]
    const int t = threadIdx.x;
    const int l = t & 63, w = t >> 6;
    const int lo = l & 15, hi = l >> 4;
    const int b  = blockIdx.x & 3;
    const int n0 = (blockIdx.x >> 2) << 6;
    f32x4 acc[4][4];
    #pragma unroll
    for (int i = 0; i < 4; ++i)
        #pragma unroll
        for (int j = 0; j < 4; ++j) acc[i][j] = (f32x4){0.f, 0.f, 0.f, 0.f};

    for (int cc = 0; cc < 8; ++cc) {
        const int c0 = cc << 6;
        for (int u = t; u < 2048; u += 256) {      // all W rows (bf16 copy)
            const int i = u >> 3, cb = (u & 7) << 4;
            const u16* src = (i < 64) ? (Wqb + (size_t)i * C_IN)
                           : (i < 128) ? (Wkb + (size_t)(i - 64) * C_IN)
                                       : (Wvb + (size_t)(i - 128) * C_IN);
            *(uint4*)swzPtr(wt, i, cb) = *(const uint4*)(src + c0 + (cb >> 1));
        }
        for (int u = t; u < 512; u += 256) {       // xb rows (already bf16)
            const int i = u >> 3, cb = (u & 7) << 4;
            *(uint4*)swzPtr(xt, i, cb) =
                *(const uint4*)(xb + ((size_t)((b << 12) + n0 + i) << 9) + c0 + (cb >> 1));
        }
        __syncthreads();
        if (w < 2) {     // Q/K: A = xt (n rows), B = wt rows w*64..
            bf16x8 af[4][2];
            #pragma unroll
            for (int tn = 0; tn < 4; ++tn) {
                af[tn][0] = *(const bf16x8*)swzPtr(xt, (tn << 4) + lo, hi << 4);
                af[tn][1] = *(const bf16x8*)swzPtr(xt, (tn << 4) + lo, 64 + (hi << 4));
            }
            #pragma unroll
            for (int to = 0; to < 4; ++to) {
                const int wr = (w << 6) + (to << 4) + lo;
                const bf16x8 bf0 = *(const bf16x8*)swzPtr(wt, wr, hi << 4);
                const bf16x8 bf1 = *(const bf16x8*)swzPtr(wt, wr, 64 + (hi << 4));
                #pragma unroll
                for (int tn = 0; tn < 4; ++tn) {
                    acc[tn][to] = __builtin_amdgcn_mfma_f32_16x16x32_bf16(af[tn][0], bf0, acc[tn][to], 0, 0, 0);
                    acc[tn][to] = __builtin_amdgcn_mfma_f32_16x16x32_bf16(af[tn][1], bf1, acc[tn][to], 0, 0, 0);
                }
            }
        } else {         // V: A = wt rows 128+(w-2)*64.., B = xt (n rows)
            bf16x8 af[4][2];
            #pragma unroll
            for (int tc = 0; tc < 4; ++tc) {
                const int wr = 128 + ((w - 2) << 6) + (tc << 4) + lo;
                af[tc][0] = *(const bf16x8*)swzPtr(wt, wr, hi << 4);
                af[tc][1] = *(const bf16x8*)swzPtr(wt, wr, 64 + (hi << 4));
            }
            #pragma unroll
            for (int tn = 0; tn < 4; ++tn) {
                const bf16x8 bf0 = *(const bf16x8*)swzPtr(xt, (tn << 4) + lo, hi << 4);
                const bf16x8 bf1 = *(const bf16x8*)swzPtr(xt, (tn << 4) + lo, 64 + (hi << 4));
                #pragma unroll
                for (int tc = 0; tc < 4; ++tc) {
                    acc[tc][tn] = __builtin_amdgcn_mfma_f32_16x16x32_bf16(af[tc][0], bf0, acc[tc][tn], 0, 0, 0);
                    acc[tc][tn] = __builtin_amdgcn_mfma_f32_16x16x32_bf16(af[tc][1], bf1, acc[tc][tn], 0, 0, 0);
                }
            }
        }
        __syncthreads();
    }
    const int kt = n0 >> 6;
    if (w == 0) {         // Q: D row = n_local, col = o
        #pragma unroll
        for (int to = 0; to < 4; ++to) {
            const float bias = bq[(to << 4) + lo];
            #pragma unroll
            for (int tn = 0; tn < 4; ++tn)
                #pragma unroll
                for (int r = 0; r < 4; ++r) {
                    const int nrow = (tn << 4) + (hi << 2) + r;
                    Qb[((size_t)((b << 12) + n0 + nrow) << 6) + (to << 4) + lo] =
                        f2bf((acc[tn][to][r] + bias) * LOG2E);
                }
        }
    } else if (w == 1) {  // K: fragment order
        #pragma unroll
        for (int to = 0; to < 4; ++to) {
            const int ch = (to << 4) + lo;
            const float bias = bk[ch];
            #pragma unroll
            for (int tn = 0; tn < 4; ++tn)
                #pragma unroll
                for (int r = 0; r < 4; ++r) {
                    const int key = (tn << 4) + (hi << 2) + r;
                    const int sid = (to << 1) + (key >> 5);
                    const int lpos = (((ch >> 3) & 1) << 5) + (key & 31);
                    Kf[(((size_t)((b << 6) + kt) << 3) + sid) * 512 + (lpos << 3) + (ch & 7)] =
                        f2bf(acc[tn][to][r] + bias);
                }
        }
    } else {              // V: fragment order; D row = cv, col = n
        #pragma unroll
        for (int tc = 0; tc < 4; ++tc)
            #pragma unroll
            for (int r = 0; r < 4; ++r) {
                const int cv = ((w - 2) << 6) + (tc << 4) + (hi << 2) + r;
                const float bias = bv[cv];
                #pragma unroll
                for (int tn = 0; tn < 4; ++tn) {
                    const int nl = (tn << 4) + lo;
                    const int sv = ((cv >> 5) << 2) + tn;
                    const int lpos = (((nl >> 3) & 1) << 5) + (cv & 31);
                    Vf[(((size_t)((b << 6) + kt) << 4) + sv) * 512 + (lpos << 3) + (nl & 7)] =
                        f2bf(acc[tc][tn][r] + bias);
                }
            }
    }
}

// ================= K2: barrier-free fragment-direct flash attention ==========
// R14 config; P^T exchange now via v_permlane32_swap_b32 (1 VALU op yields
// BOTH fragment words; replaces 8 ds_bpermute + lgkm waits on critical path).

#define KLOAD(dst, ktl)                                                        \
    {                                                                          \
        const size_t o_ = ((size_t)(((s << 4) + ((ktl) & 15)) << 3)) * 512;    \
        _Pragma("unroll")                                                      \
        for (int i_ = 0; i_ < 8; ++i_)                                         \
            dst[i_] = *(const bf16x8*)(kfb + o_ + i_ * 512);                   \
    }

#define VLOAD(dst, ktl, tjIdx)                                                 \
    {                                                                          \
        const size_t o_ = ((size_t)(((s << 4) + (ktl)) << 4) + ((tjIdx) << 2)) * 512; \
        _Pragma("unroll")                                                      \
        for (int i_ = 0; i_ < 4; ++i_)                                         \
            dst[i_] = *(const bf16x8*)(vfb + o_ + i_ * 512);                   \
    }

#define TILE(kt, kfU, kfP)                                                    \
    {                                                                         \
        bf16x8 vA[4], vB[4], vC[4];                                           \
        VLOAD(vA, kt, 0);                                                     \
        f32x16 sa0, sa1;                                                      \
        _Pragma("unroll")                                                     \
        for (int i = 0; i < 16; ++i) { sa0[i] = 0.f; sa1[i] = 0.f; }          \
        __builtin_amdgcn_s_setprio(1);                                        \
        _Pragma("unroll")                                                     \
        for (int ks = 0; ks < 4; ++ks) {                                      \
            sa0 = __builtin_amdgcn_mfma_f32_32x32x16_bf16(kfU[(ks << 1)], qf[ks], sa0, 0, 0, 0);     \
            sa1 = __builtin_amdgcn_mfma_f32_32x32x16_bf16(kfU[(ks << 1) + 1], qf[ks], sa1, 0, 0, 0); \
        }                                                                     \
        __builtin_amdgcn_s_setprio(0);                                        \
        KLOAD(kfP, (kt) + 1);                                                 \
        VLOAD(vB, kt, 1);                                                     \
        float p0[16], p1[16];                                                 \
        _Pragma("unroll")                                                     \
        for (int i = 0; i < 16; ++i) {                                        \
            p0[i] = exp2f(sa0[i]);                                            \
            p1[i] = exp2f(sa1[i]);                                            \
        }                                                                     \
        float sm8[8];                                                         \
        _Pragma("unroll")                                                     \
        for (int i = 0; i < 8; ++i) sm8[i] = (p0[i] + p0[i + 8]) + (p1[i] + p1[i + 8]); \
        _Pragma("unroll")                                                     \
        for (int i = 0; i < 4; ++i) sm8[i] += sm8[i + 4];                     \
        lsum += (sm8[0] + sm8[1]) + (sm8[2] + sm8[3]);                        \
        VLOAD(vC, kt, 2);                                                     \
        uint32_t P2[2][4][2];                                                 \
        _Pragma("unroll")                                                     \
        for (int g = 0; g < 4; ++g) {                                         \
            _Pragma("unroll")                                                 \
            for (int pr = 0; pr < 2; ++pr) {                                  \
                asm("v_cvt_pk_bf16_f32 %0, %1, %2"                            \
                    : "=v"(P2[0][g][pr]) : "v"(p0[4 * g + 2 * pr]), "v"(p0[4 * g + 2 * pr + 1])); \
                asm("v_cvt_pk_bf16_f32 %0, %1, %2"                            \
                    : "=v"(P2[1][g][pr]) : "v"(p1[4 * g + 2 * pr]), "v"(p1[4 * g + 2 * pr + 1])); \
            }                                                                 \
        }                                                                     \
        bf16x8 pf[4];                                                         \
        _Pragma("unroll")                                                     \
        for (int ks = 0; ks < 4; ++ks) {                                      \
            const int iE = ks << 1, iO = iE + 1;                              \
            uint32_t fr[4];                                                   \
            _Pragma("unroll")                                                 \
            for (int pr = 0; pr < 2; ++pr) {                                  \
                uint32_t X = P2[iE >> 2][iE & 3][pr];                         \
                uint32_t Y = P2[iO >> 2][iO & 3][pr];                         \
                asm("v_permlane32_swap_b32 %0, %1" : "+v"(X), "+v"(Y));       \
                fr[pr]     = X;       /* {X_lo | Y_lo} */                     \
                fr[2 + pr] = Y;       /* {X_hi | Y_hi} */                     \
            }                                                                 \
            pf[ks] = *(bf16x8*)fr;                                            \
        }                                                                     \
        __builtin_amdgcn_s_setprio(1);                                        \
        _Pragma("unroll")                                                     \
        for (int ks = 0; ks < 4; ++ks)                                        \
            oacc[0] = __builtin_amdgcn_mfma_f32_32x32x16_bf16(vA[ks], pf[ks], oacc[0], 0, 0, 0); \
        __builtin_amdgcn_s_setprio(0);                                        \
        VLOAD(vA, kt, 3);                                                     \
        __builtin_amdgcn_s_setprio(1);                                        \
        _Pragma("unroll")                                                     \
        for (int ks = 0; ks < 4; ++ks)                                        \
            oacc[1] = __builtin_amdgcn_mfma_f32_32x32x16_bf16(vB[ks], pf[ks], oacc[1], 0, 0, 0); \
        _Pragma("unroll")                                                     \
        for (int ks = 0; ks < 4; ++ks)                                        \
            oacc[2] = __builtin_amdgcn_mfma_f32_32x32x16_bf16(vC[ks], pf[ks], oacc[2], 0, 0, 0); \
        _Pragma("unroll")                                                     \
        for (int ks = 0; ks < 4; ++ks)                                        \
            oacc[3] = __builtin_amdgcn_mfma_f32_32x32x16_bf16(vA[ks], pf[ks], oacc[3], 0, 0, 0); \
        __builtin_amdgcn_s_setprio(0);                                        \
    }

__global__ __launch_bounds__(256, 2) void attn_kernel(
    const u16* __restrict__ Qb, const u16* __restrict__ Kf,
    const u16* __restrict__ Vf, u16* __restrict__ po,
    float* __restrict__ pl)
{
    const int t = threadIdx.x;
    const int l = t & 63, w = t >> 6;          // 4 waves
    const int l31 = l & 31, h = l >> 5;
    const int b = blockIdx.x & 3;
    const int s = (blockIdx.x >> 2) & 3;       // 4-way KV split
    const int qc = blockIdx.x >> 4;
    const int n0 = qc << 7;                    // 128 q per block

    const u16* qp = Qb + ((size_t)((b << 12) + n0 + (w << 5) + l31) << 6) + (h << 3);
    bf16x8 qf[4];
    #pragma unroll
    for (int ks = 0; ks < 4; ++ks) qf[ks] = *(const bf16x8*)(qp + (ks << 4));

    const u16* kfb = Kf + (((size_t)(b << 6)) << 12) + (l << 3);
    const u16* vfb = Vf + (((size_t)(b << 6)) << 13) + (l << 3);

    float lsum = 0.f;
    f32x16 oacc[4];
    #pragma unroll
    for (int tj = 0; tj < 4; ++tj)
        #pragma unroll
        for (int i = 0; i < 16; ++i) oacc[tj][i] = 0.f;

    bf16x8 kfA[8], kfB[8];
    KLOAD(kfA, 0);

    for (int kt2 = 0; kt2 < 16; kt2 += 2) {
        TILE(kt2, kfA, kfB);
        TILE(kt2 + 1, kfB, kfA);
    }

    lsum += __shfl_xor(lsum, 32);
    u16* pod = po + ((size_t)blockIdx.x << 14);   // [128 cv][128 q]
    #pragma unroll
    for (int tj = 0; tj < 4; ++tj)
        #pragma unroll
        for (int r = 0; r < 16; ++r) {
            const int cv = (tj << 5) + (r & 3) + ((r >> 2) << 3) + (h << 2);
            pod[(cv << 7) + (w << 5) + l31] = f2bf(oacc[tj][r]);
        }
    if (h == 0) pl[(blockIdx.x << 7) + (w << 5) + l31] = lsum;
}

// ---------------- K2b: combine (pure sum of 4 splits) -> Ob[b][n][cv] bf16 ---
__global__ __launch_bounds__(256) void combine_kernel(
    const u16* __restrict__ po, const float* __restrict__ pl,
    u16* __restrict__ Ob)
{
    __shared__ float invl[128];
    __shared__ float tr[64][132];
    const int t = threadIdx.x;
    const int b = blockIdx.x & 3;
    const int qc = blockIdx.x >> 2;            // 0..31 (128-q chunks)
    int slot[4];
    #pragma unroll
    for (int s = 0; s < 4; ++s) slot[s] = b + (s << 2) + (qc << 4);
    if (t < 128) {
        float lg = 0.f;
        #pragma unroll
        for (int s = 0; s < 4; ++s) lg += pl[(slot[s] << 7) + t];
        invl[t] = 1.0f / lg;
    }
    __syncthreads();
    #pragma unroll
    for (int qh = 0; qh < 2; ++qh) {
        for (int u = t; u < 2048; u += 256) {           // accumulate -> LDS [q][cv]
            const int cv = u >> 4, q4 = (u & 15) << 2;
            const int q = (qh << 6) + q4;
            float a0 = 0.f, a1 = 0.f, a2 = 0.f, a3 = 0.f;
            #pragma unroll
            for (int s = 0; s < 4; ++s) {
                const ushort4 hv =
                    *(const ushort4*)(po + ((size_t)slot[s] << 14) + (cv << 7) + q);
                a0 += bf2f(hv.x); a1 += bf2f(hv.y);
                a2 += bf2f(hv.z); a3 += bf2f(hv.w);
            }
            tr[q4 + 0][cv] = a0 * invl[q];
            tr[q4 + 1][cv] = a1 * invl[q + 1];
            tr[q4 + 2][cv] = a2 * invl[q + 2];
            tr[q4 + 3][cv] = a3 * invl[q + 3];
        }
        __syncthreads();
        for (int u = t; u < 2048; u += 256) {           // write [n][cv] bf16
            const int q = u >> 5, c4 = (u & 31) << 2;
            const float4 v = *(const float4*)&tr[q][c4];
            ushort4 o;
            o.x = f2bf(v.x); o.y = f2bf(v.y); o.z = f2bf(v.z); o.w = f2bf(v.w);
            const int n = (qc << 7) + (qh << 6) + q;
            *(ushort4*)(Ob + ((size_t)((b << 12) + n) << 7) + c4) = o;
        }
        __syncthreads();
    }
}

// ---------------- K3: output projection + residual, bf16 MFMA (bf16 Wo) ------
__global__ __launch_bounds__(256) void proj_kernel(
    const u16* __restrict__ Ob, const u16* __restrict__ Wob,
    const float* __restrict__ bo, const float* __restrict__ x,
    const float* __restrict__ gamma_p, float* __restrict__ out)
{
    __shared__ union {
        struct { u16 wl0[64 * 64]; u16 wl1[64 * 64]; u16 ob0[64 * 64]; u16 ob1[64 * 64]; } s;
        float tr[64 * 64];
    } sm;
    const int t = threadIdx.x;
    const int l = t & 63, w = t >> 6;
    const int lo = l & 15, hi = l >> 4;
    const int b  = blockIdx.x & 3;
    const int co0 = ((blockIdx.x >> 2) & 7) << 6;
    const int n0  = (blockIdx.x >> 5) << 6;
    for (int u = t; u < 1024; u += 256) {      // Wo rows (bf16, plain copy)
        const int i = u >> 4, cb = (u & 15) << 4;
        *(uint4*)swzPtr((cb < 128) ? sm.s.wl0 : sm.s.wl1, i, cb & 127) =
            *(const uint4*)(Wob + (size_t)(co0 + i) * C_V + (cb >> 1));
    }
    for (int u = t; u < 1024; u += 256) {
        const int i = u >> 4, cb = (u & 15) << 4;
        *(uint4*)swzPtr((cb < 128) ? sm.s.ob0 : sm.s.ob1, i, cb & 127) =
            *(const uint4*)(Ob + ((size_t)((b << 12) + n0 + i) << 7) + (cb >> 1));
    }
    __syncthreads();
    const int arow = (w << 4) + lo;
    const bf16x8 af00 = *(const bf16x8*)swzPtr(sm.s.wl0, arow, hi << 4);
    const bf16x8 af01 = *(const bf16x8*)swzPtr(sm.s.wl0, arow, 64 + (hi << 4));
    const bf16x8 af10 = *(const bf16x8*)swzPtr(sm.s.wl1, arow, hi << 4);
    const bf16x8 af11 = *(const bf16x8*)swzPtr(sm.s.wl1, arow, 64 + (hi << 4));
    f32x4 acc[4];
    #pragma unroll
    for (int ti = 0; ti < 4; ++ti) {
        const int brow = (ti << 4) + lo;
        f32x4 z = (f32x4){0.f, 0.f, 0.f, 0.f};
        z = __builtin_amdgcn_mfma_f32_16x16x32_bf16(af00, *(const bf16x8*)swzPtr(sm.s.ob0, brow, hi << 4), z, 0, 0, 0);
        z = __builtin_amdgcn_mfma_f32_16x16x32_bf16(af01, *(const bf16x8*)swzPtr(sm.s.ob0, brow, 64 + (hi << 4)), z, 0, 0, 0);
        z = __builtin_amdgcn_mfma_f32_16x16x32_bf16(af10, *(const bf16x8*)swzPtr(sm.s.ob1, brow, hi << 4), z, 0, 0, 0);
        acc[ti] = __builtin_amdgcn_mfma_f32_16x16x32_bf16(af11, *(const bf16x8*)swzPtr(sm.s.ob1, brow, 64 + (hi << 4)), z, 0, 0, 0);
    }
    __syncthreads();
    #pragma unroll
    for (int ti = 0; ti < 4; ++ti)
        #pragma unroll
        for (int r = 0; r < 4; ++r) {
            const int co = (w << 4) + (hi << 2) + r;
            const int n  = (ti << 4) + lo;
            sm.tr[(co << 6) + (n ^ (((co >> 2) & 3) << 2))] = acc[ti][r];
        }
    __syncthreads();
    const float g = gamma_p[0];
    for (int u = t; u < 1024; u += 256) {
        const int co = u >> 4, n4 = (u & 15) << 2;
        const float4 av = *(const float4*)&sm.tr[(co << 6) + (n4 ^ (((co >> 2) & 3) << 2))];
        const int o = co0 + co;
        const size_t off = ((size_t)(b * C_IN + o) << 12) + n0 + n4;
        const float4 xv = *(const float4*)(x + off);
        const float bias = bo[o];
        float4 rs;
        rs.x = xv.x + g * (av.x + bias);
        rs.y = xv.y + g * (av.y + bias);
        rs.z = xv.z + g * (av.z + bias);
        rs.w = xv.w + g * (av.w + bias);
        *(float4*)(out + off) = rs;
    }
}

extern "C" void kernel_launch(void* const* d_in, const int* in_sizes, int n_in,
                              void* d_out, int out_size, void* d_ws, size_t ws_size,
                              hipStream_t stream) {
    (void)in_sizes; (void)n_in; (void)out_size; (void)ws_size;
    const float* x  = (const float*)d_in[0];
    const float* Wq = (const float*)d_in[1];
    const float* bq = (const float*)d_in[2];
    const float* Wk = (const float*)d_in[3];
    const float* bk = (const float*)d_in[4];
    const float* Wv = (const float*)d_in[5];
    const float* bv = (const float*)d_in[6];
    const float* Wo = (const float*)d_in[7];
    const float* bo = (const float*)d_in[8];
    const float* gm = (const float*)d_in[9];
    float* out = (float*)d_out;
    // ws layout (bytes), total ~28.7 MB:
    //   [0,16M):  xb bf16 (K0->K1, dead after) ALIASED with po bf16 (512 x 32KB)
    //   [16,18M) Qb | [18,20M) Kf | [20,24M) Vf | [24M,+256K) pl | [+,+4M) Ob
    //   [28.25M,+384K) Wqb 64K | Wkb 64K | Wvb 128K | Wob 128K
    u16* xb = (u16*)d_ws;
    u16* po = (u16*)d_ws;                        // alias: xb dead after K1
    u16* Qb = (u16*)((char*)d_ws + ((size_t)16 << 20));
    u16* Kf = Qb + (size_t)4 * N_SP * C_QK;
    u16* Vf = Kf + (size_t)4 * N_SP * C_QK;
    float* pl = (float*)((char*)d_ws + ((size_t)24 << 20));
    u16* Ob = (u16*)((char*)d_ws + ((size_t)24 << 20) + (256 << 10));
    u16* Wqb = (u16*)((char*)d_ws + ((size_t)24 << 20) + (256 << 10) + ((size_t)4 << 20));
    u16* Wkb = Wqb + 64 * 512;
    u16* Wvb = Wkb + 64 * 512;
    u16* Wob = Wvb + 128 * 512;
    wconv_kernel<<<192, 256, 0, stream>>>(Wq, Wk, Wv, Wo, Wqb, Wkb, Wvb, Wob);
    transpose_kernel<<<2048, 256, 0, stream>>>(x, xb);
    qkv_kernel<<<256, 256, 0, stream>>>(xb, Wqb, bq, Wkb, bk, Wvb, bv, Qb, Kf, Vf);
    attn_kernel<<<512, 256, 0, stream>>>(Qb, Kf, Vf, po, pl);
    combine_kernel<<<128, 256, 0, stream>>>(po, pl, Ob);
    proj_kernel<<<2048, 256, 0, stream>>>(Ob, Wob, bo, x, gm, out);
}

// Round 16
// 104.366 us; speedup vs baseline: 1.1333x; 1.1333x over previous
//
#include <hip/hip_runtime.h>
#include <cstdint>
#include <cstddef>

#define N_SP 4096
#define C_IN 512
#define C_QK 64
#define C_V  128
#define LOG2E 1.4426950408889634f

typedef unsigned short u16;
typedef __attribute__((ext_vector_type(8))) short bf16x8;
typedef __attribute__((ext_vector_type(4))) float f32x4;
typedef __attribute__((ext_vector_type(16))) float f32x16;

__device__ __forceinline__ u16 f2bf(float f) {
    union { float f; uint32_t u; } x; x.f = f;
    const uint32_t r = x.u + 0x7fffu + ((x.u >> 16) & 1u);
    return (u16)(r >> 16);
}
__device__ __forceinline__ float bf2f(u16 b) {
    union { uint32_t u; float f; } x; x.u = ((uint32_t)b) << 16;
    return x.f;
}

// Swizzled pointer into a 128-byte-row LDS tile: byte ^= (row&7)<<4. (K0/K1/K3 only)
__device__ __forceinline__ void* swzPtr(const void* base, int row, int colByte) {
    return (char*)base + row * 128 + (colByte ^ ((row & 7) << 4));
}

// ---------------- Kw: one-shot weight conversion f32 -> bf16 ----------------
__global__ __launch_bounds__(256) void wconv_kernel(
    const float* __restrict__ Wq, const float* __restrict__ Wk,
    const float* __restrict__ Wv, const float* __restrict__ Wo,
    u16* __restrict__ Wqb, u16* __restrict__ Wkb,
    u16* __restrict__ Wvb, u16* __restrict__ Wob)
{
    const int i = (blockIdx.x << 8) + threadIdx.x;   // quad index, grid 192
    const float* src; u16* dst; int off;
    if (i < 8192)       { src = Wq; dst = Wqb; off = i; }
    else if (i < 16384) { src = Wk; dst = Wkb; off = i - 8192; }
    else if (i < 32768) { src = Wv; dst = Wvb; off = i - 16384; }
    else                { src = Wo; dst = Wob; off = i - 32768; }
    const float4 v = *(const float4*)(src + ((size_t)off << 2));
    ushort4 h;
    h.x = f2bf(v.x); h.y = f2bf(v.y); h.z = f2bf(v.z); h.w = f2bf(v.w);
    *(ushort4*)(dst + ((size_t)off << 2)) = h;
}

// ---------------- K0: transpose-convert x[b][c][n] f32 -> xb[b][n][c] bf16 ----
__global__ __launch_bounds__(256) void transpose_kernel(
    const float* __restrict__ x, u16* __restrict__ xb)
{
    __shared__ u16 ts[64 * 64];
    const int t = threadIdx.x;
    const int b  = blockIdx.x & 3;
    const int cc = (blockIdx.x >> 2) & 7;
    const int nc = blockIdx.x >> 5;
    const int c0 = cc << 6, n0 = nc << 6;
    const float* xs = x + ((size_t)(b * C_IN + c0) << 12) + n0;
    for (int u = t; u < 1024; u += 256) {
        const int c = u >> 4, nq = (u & 15) << 2;
        const float4 v = *(const float4*)(xs + ((size_t)c << 12) + nq);
        ushort4 h;
        h.x = f2bf(v.x); h.y = f2bf(v.y); h.z = f2bf(v.z); h.w = f2bf(v.w);
        *(ushort4*)((char*)ts + c * 128 + ((nq << 1) ^ (((c >> 3) & 7) << 4))) = h;
    }
    __syncthreads();
    for (int u = t; u < 512; u += 256) {
        const int n = u >> 3, cg = u & 7;
        u16 pk[8];
        #pragma unroll
        for (int j = 0; j < 8; ++j) {
            const int c = (cg << 3) + j;
            pk[j] = *(const u16*)((char*)ts + c * 128 + ((n << 1) ^ (cg << 4)));
        }
        *(ushort4*)(xb + ((size_t)((b << 12) + n0 + n) << 9) + c0 + (cg << 3)) =
            *(ushort4*)&pk[0];
        *(ushort4*)(xb + ((size_t)((b << 12) + n0 + n) << 9) + c0 + (cg << 3) + 4) =
            *(ushort4*)&pk[4];
    }
}

// ---------------- K1: QKV projection, bf16 MFMA (bf16 weights, R14 form) -----
// Q -> Qb[b][n][64] (*log2e). K,V -> fragment-ordered Kf/Vf (see R10).
__global__ __launch_bounds__(256) void qkv_kernel(
    const u16* __restrict__ xb,
    const u16* __restrict__ Wqb, const float* __restrict__ bq,
    const u16* __restrict__ Wkb, const float* __restrict__ bk,
    const u16* __restrict__ Wvb, const float* __restrict__ bv,
    u16* __restrict__ Qb, u16* __restrict__ Kf, u16* __restrict__ Vf)
{
    __shared__ u16 wt[64 * 64];   // W chunk  [o][64 c]
    __shared__ u16 xt[64 * 64];   // xb chunk [n][64 c]
    const int t = threadIdx.x;
    const int l = t & 63, w = t >> 6;
    const int lo = l & 15, hi = l >> 4;
    const int b  = blockIdx.x & 3;
    const int ot = (blockIdx.x >> 2) & 3;
    const int n0 = (blockIdx.x >> 4) << 6;
    const u16* Wbase = (ot == 0) ? Wqb : (ot == 1) ? Wkb : (Wvb + ((ot - 2) << 6) * C_IN);
    f32x4 acc[4];
    #pragma unroll
    for (int ti = 0; ti < 4; ++ti) acc[ti] = (f32x4){0.f, 0.f, 0.f, 0.f};

    for (int cc = 0; cc < 8; ++cc) {
        const int c0 = cc << 6;
        for (int u = t; u < 512; u += 256) {       // W rows (bf16, plain copy)
            const int i = u >> 3, cb = (u & 7) << 4;
            *(uint4*)swzPtr(wt, i, cb) =
                *(const uint4*)(Wbase + (size_t)i * C_IN + c0 + (cb >> 1));
        }
        for (int u = t; u < 512; u += 256) {       // xb rows (already bf16)
            const int i = u >> 3, cb = (u & 7) << 4;
            *(uint4*)swzPtr(xt, i, cb) =
                *(const uint4*)(xb + ((size_t)((b << 12) + n0 + i) << 9) + c0 + (cb >> 1));
        }
        __syncthreads();
        if (ot < 2) {
            const bf16x8 af0 = *(const bf16x8*)swzPtr(xt, (w << 4) + lo, hi << 4);
            const bf16x8 af1 = *(const bf16x8*)swzPtr(xt, (w << 4) + lo, 64 + (hi << 4));
            #pragma unroll
            for (int ti = 0; ti < 4; ++ti) {
                const bf16x8 bf0 = *(const bf16x8*)swzPtr(wt, (ti << 4) + lo, hi << 4);
                const bf16x8 bf1 = *(const bf16x8*)swzPtr(wt, (ti << 4) + lo, 64 + (hi << 4));
                acc[ti] = __builtin_amdgcn_mfma_f32_16x16x32_bf16(af0, bf0, acc[ti], 0, 0, 0);
                acc[ti] = __builtin_amdgcn_mfma_f32_16x16x32_bf16(af1, bf1, acc[ti], 0, 0, 0);
            }
        } else {
            const bf16x8 af0 = *(const bf16x8*)swzPtr(wt, (w << 4) + lo, hi << 4);
            const bf16x8 af1 = *(const bf16x8*)swzPtr(wt, (w << 4) + lo, 64 + (hi << 4));
            #pragma unroll
            for (int ti = 0; ti < 4; ++ti) {
                const bf16x8 bf0 = *(const bf16x8*)swzPtr(xt, (ti << 4) + lo, hi << 4);
                const bf16x8 bf1 = *(const bf16x8*)swzPtr(xt, (ti << 4) + lo, 64 + (hi << 4));
                acc[ti] = __builtin_amdgcn_mfma_f32_16x16x32_bf16(af0, bf0, acc[ti], 0, 0, 0);
                acc[ti] = __builtin_amdgcn_mfma_f32_16x16x32_bf16(af1, bf1, acc[ti], 0, 0, 0);
            }
        }
        __syncthreads();
    }
    const int kt = n0 >> 6;
    if (ot == 0) {        // Q: D row = n_local, col = ch -> Qb[n][64ch], *log2e
        #pragma unroll
        for (int ti = 0; ti < 4; ++ti) {
            const float bias = bq[(ti << 4) + lo];
            #pragma unroll
            for (int r = 0; r < 4; ++r) {
                const int nrow = (w << 4) + (hi << 2) + r;
                Qb[((size_t)((b << 12) + n0 + nrow) << 6) + (ti << 4) + lo] =
                    f2bf((acc[ti][r] + bias) * LOG2E);
            }
        }
    } else if (ot == 1) { // K: fragment order
        #pragma unroll
        for (int ti = 0; ti < 4; ++ti) {
            const int ch = (ti << 4) + lo;
            const float bias = bk[ch];
            #pragma unroll
            for (int r = 0; r < 4; ++r) {
                const int key = (w << 4) + (hi << 2) + r;   // D row = key local
                const int sid = (ti << 1) + (key >> 5);
                const int lpos = (((ch >> 3) & 1) << 5) + (key & 31);
                Kf[(((size_t)((b << 6) + kt) << 3) + sid) * 512 + (lpos << 3) + (ch & 7)] =
                    f2bf(acc[ti][r] + bias);
            }
        }
    } else {              // V: fragment order (D row = cv local, col = n local)
        #pragma unroll
        for (int r = 0; r < 4; ++r) {
            const int cv = ((ot - 2) << 6) + (w << 4) + (hi << 2) + r;
            const float bias = bv[cv];
            #pragma unroll
            for (int ti = 0; ti < 4; ++ti) {
                const int nl = (ti << 4) + lo;              // n local to 64-tile
                const int sv = ((cv >> 5) << 2) + ti;
                const int lpos = (((nl >> 3) & 1) << 5) + (cv & 31);
                Vf[(((size_t)((b << 6) + kt) << 4) + sv) * 512 + (lpos << 3) + (nl & 7)] =
                    f2bf(acc[ti][r] + bias);
            }
        }
    }
}

// ================= K2: barrier-free fragment-direct flash attention ==========
// R14 config; P^T exchange via v_permlane32_swap_b32 (R15's verified win).

#define KLOAD(dst, ktl)                                                        \
    {                                                                          \
        const size_t o_ = ((size_t)(((s << 4) + ((ktl) & 15)) << 3)) * 512;    \
        _Pragma("unroll")                                                      \
        for (int i_ = 0; i_ < 8; ++i_)                                         \
            dst[i_] = *(const bf16x8*)(kfb + o_ + i_ * 512);                   \
    }

#define VLOAD(dst, ktl, tjIdx)                                                 \
    {                                                                          \
        const size_t o_ = ((size_t)(((s << 4) + (ktl)) << 4) + ((tjIdx) << 2)) * 512; \
        _Pragma("unroll")                                                      \
        for (int i_ = 0; i_ < 4; ++i_)                                         \
            dst[i_] = *(const bf16x8*)(vfb + o_ + i_ * 512);                   \
    }

#define TILE(kt, kfU, kfP)                                                    \
    {                                                                         \
        bf16x8 vA[4], vB[4], vC[4];                                           \
        VLOAD(vA, kt, 0);                                                     \
        f32x16 sa0, sa1;                                                      \
        _Pragma("unroll")                                                     \
        for (int i = 0; i < 16; ++i) { sa0[i] = 0.f; sa1[i] = 0.f; }          \
        __builtin_amdgcn_s_setprio(1);                                        \
        _Pragma("unroll")                                                     \
        for (int ks = 0; ks < 4; ++ks) {                                      \
            sa0 = __builtin_amdgcn_mfma_f32_32x32x16_bf16(kfU[(ks << 1)], qf[ks], sa0, 0, 0, 0);     \
            sa1 = __builtin_amdgcn_mfma_f32_32x32x16_bf16(kfU[(ks << 1) + 1], qf[ks], sa1, 0, 0, 0); \
        }                                                                     \
        __builtin_amdgcn_s_setprio(0);                                        \
        KLOAD(kfP, (kt) + 1);                                                 \
        VLOAD(vB, kt, 1);                                                     \
        float p0[16], p1[16];                                                 \
        _Pragma("unroll")                                                     \
        for (int i = 0; i < 16; ++i) {                                        \
            p0[i] = exp2f(sa0[i]);                                            \
            p1[i] = exp2f(sa1[i]);                                            \
        }                                                                     \
        float sm8[8];                                                         \
        _Pragma("unroll")                                                     \
        for (int i = 0; i < 8; ++i) sm8[i] = (p0[i] + p0[i + 8]) + (p1[i] + p1[i + 8]); \
        _Pragma("unroll")                                                     \
        for (int i = 0; i < 4; ++i) sm8[i] += sm8[i + 4];                     \
        lsum += (sm8[0] + sm8[1]) + (sm8[2] + sm8[3]);                        \
        VLOAD(vC, kt, 2);                                                     \
        uint32_t P2[2][4][2];                                                 \
        _Pragma("unroll")                                                     \
        for (int g = 0; g < 4; ++g) {                                         \
            _Pragma("unroll")                                                 \
            for (int pr = 0; pr < 2; ++pr) {                                  \
                asm("v_cvt_pk_bf16_f32 %0, %1, %2"                            \
                    : "=v"(P2[0][g][pr]) : "v"(p0[4 * g + 2 * pr]), "v"(p0[4 * g + 2 * pr + 1])); \
                asm("v_cvt_pk_bf16_f32 %0, %1, %2"                            \
                    : "=v"(P2[1][g][pr]) : "v"(p1[4 * g + 2 * pr]), "v"(p1[4 * g + 2 * pr + 1])); \
            }                                                                 \
        }                                                                     \
        bf16x8 pf[4];                                                         \
        _Pragma("unroll")                                                     \
        for (int ks = 0; ks < 4; ++ks) {                                      \
            const int iE = ks << 1, iO = iE + 1;                              \
            uint32_t fr[4];                                                   \
            _Pragma("unroll")                                                 \
            for (int pr = 0; pr < 2; ++pr) {                                  \
                uint32_t X = P2[iE >> 2][iE & 3][pr];                         \
                uint32_t Y = P2[iO >> 2][iO & 3][pr];                         \
                asm("v_permlane32_swap_b32 %0, %1" : "+v"(X), "+v"(Y));       \
                fr[pr]     = X;       /* {X_lo | Y_lo} */                     \
                fr[2 + pr] = Y;       /* {X_hi | Y_hi} */                     \
            }                                                                 \
            pf[ks] = *(bf16x8*)fr;                                            \
        }                                                                     \
        __builtin_amdgcn_s_setprio(1);                                        \
        _Pragma("unroll")                                                     \
        for (int ks = 0; ks < 4; ++ks)                                        \
            oacc[0] = __builtin_amdgcn_mfma_f32_32x32x16_bf16(vA[ks], pf[ks], oacc[0], 0, 0, 0); \
        __builtin_amdgcn_s_setprio(0);                                        \
        VLOAD(vA, kt, 3);                                                     \
        __builtin_amdgcn_s_setprio(1);                                        \
        _Pragma("unroll")                                                     \
        for (int ks = 0; ks < 4; ++ks)                                        \
            oacc[1] = __builtin_amdgcn_mfma_f32_32x32x16_bf16(vB[ks], pf[ks], oacc[1], 0, 0, 0); \
        _Pragma("unroll")                                                     \
        for (int ks = 0; ks < 4; ++ks)                                        \
            oacc[2] = __builtin_amdgcn_mfma_f32_32x32x16_bf16(vC[ks], pf[ks], oacc[2], 0, 0, 0); \
        _Pragma("unroll")                                                     \
        for (int ks = 0; ks < 4; ++ks)                                        \
            oacc[3] = __builtin_amdgcn_mfma_f32_32x32x16_bf16(vA[ks], pf[ks], oacc[3], 0, 0, 0); \
        __builtin_amdgcn_s_setprio(0);                                        \
    }

__global__ __launch_bounds__(256, 2) void attn_kernel(
    const u16* __restrict__ Qb, const u16* __restrict__ Kf,
    const u16* __restrict__ Vf, u16* __restrict__ po,
    float* __restrict__ pl)
{
    const int t = threadIdx.x;
    const int l = t & 63, w = t >> 6;          // 4 waves
    const int l31 = l & 31, h = l >> 5;
    const int b = blockIdx.x & 3;
    const int s = (blockIdx.x >> 2) & 3;       // 4-way KV split
    const int qc = blockIdx.x >> 4;
    const int n0 = qc << 7;                    // 128 q per block

    const u16* qp = Qb + ((size_t)((b << 12) + n0 + (w << 5) + l31) << 6) + (h << 3);
    bf16x8 qf[4];
    #pragma unroll
    for (int ks = 0; ks < 4; ++ks) qf[ks] = *(const bf16x8*)(qp + (ks << 4));

    const u16* kfb = Kf + (((size_t)(b << 6)) << 12) + (l << 3);
    const u16* vfb = Vf + (((size_t)(b << 6)) << 13) + (l << 3);

    float lsum = 0.f;
    f32x16 oacc[4];
    #pragma unroll
    for (int tj = 0; tj < 4; ++tj)
        #pragma unroll
        for (int i = 0; i < 16; ++i) oacc[tj][i] = 0.f;

    bf16x8 kfA[8], kfB[8];
    KLOAD(kfA, 0);

    for (int kt2 = 0; kt2 < 16; kt2 += 2) {
        TILE(kt2, kfA, kfB);
        TILE(kt2 + 1, kfB, kfA);
    }

    lsum += __shfl_xor(lsum, 32);
    u16* pod = po + ((size_t)blockIdx.x << 14);   // [128 cv][128 q]
    #pragma unroll
    for (int tj = 0; tj < 4; ++tj)
        #pragma unroll
        for (int r = 0; r < 16; ++r) {
            const int cv = (tj << 5) + (r & 3) + ((r >> 2) << 3) + (h << 2);
            pod[(cv << 7) + (w << 5) + l31] = f2bf(oacc[tj][r]);
        }
    if (h == 0) pl[(blockIdx.x << 7) + (w << 5) + l31] = lsum;
}

// ---------------- K2b: combine (pure sum of 4 splits) -> Ob[b][n][cv] bf16 ---
__global__ __launch_bounds__(256) void combine_kernel(
    const u16* __restrict__ po, const float* __restrict__ pl,
    u16* __restrict__ Ob)
{
    __shared__ float invl[128];
    __shared__ float tr[64][132];
    const int t = threadIdx.x;
    const int b = blockIdx.x & 3;
    const int qc = blockIdx.x >> 2;            // 0..31 (128-q chunks)
    int slot[4];
    #pragma unroll
    for (int s = 0; s < 4; ++s) slot[s] = b + (s << 2) + (qc << 4);
    if (t < 128) {
        float lg = 0.f;
        #pragma unroll
        for (int s = 0; s < 4; ++s) lg += pl[(slot[s] << 7) + t];
        invl[t] = 1.0f / lg;
    }
    __syncthreads();
    #pragma unroll
    for (int qh = 0; qh < 2; ++qh) {
        for (int u = t; u < 2048; u += 256) {           // accumulate -> LDS [q][cv]
            const int cv = u >> 4, q4 = (u & 15) << 2;
            const int q = (qh << 6) + q4;
            float a0 = 0.f, a1 = 0.f, a2 = 0.f, a3 = 0.f;
            #pragma unroll
            for (int s = 0; s < 4; ++s) {
                const ushort4 hv =
                    *(const ushort4*)(po + ((size_t)slot[s] << 14) + (cv << 7) + q);
                a0 += bf2f(hv.x); a1 += bf2f(hv.y);
                a2 += bf2f(hv.z); a3 += bf2f(hv.w);
            }
            tr[q4 + 0][cv] = a0 * invl[q];
            tr[q4 + 1][cv] = a1 * invl[q + 1];
            tr[q4 + 2][cv] = a2 * invl[q + 2];
            tr[q4 + 3][cv] = a3 * invl[q + 3];
        }
        __syncthreads();
        for (int u = t; u < 2048; u += 256) {           // write [n][cv] bf16
            const int q = u >> 5, c4 = (u & 31) << 2;
            const float4 v = *(const float4*)&tr[q][c4];
            ushort4 o;
            o.x = f2bf(v.x); o.y = f2bf(v.y); o.z = f2bf(v.z); o.w = f2bf(v.w);
            const int n = (qc << 7) + (qh << 6) + q;
            *(ushort4*)(Ob + ((size_t)((b << 12) + n) << 7) + c4) = o;
        }
        __syncthreads();
    }
}

// ---------------- K3: output projection + residual, bf16 MFMA (bf16 Wo) ------
__global__ __launch_bounds__(256) void proj_kernel(
    const u16* __restrict__ Ob, const u16* __restrict__ Wob,
    const float* __restrict__ bo, const float* __restrict__ x,
    const float* __restrict__ gamma_p, float* __restrict__ out)
{
    __shared__ union {
        struct { u16 wl0[64 * 64]; u16 wl1[64 * 64]; u16 ob0[64 * 64]; u16 ob1[64 * 64]; } s;
        float tr[64 * 64];
    } sm;
    const int t = threadIdx.x;
    const int l = t & 63, w = t >> 6;
    const int lo = l & 15, hi = l >> 4;
    const int b  = blockIdx.x & 3;
    const int co0 = ((blockIdx.x >> 2) & 7) << 6;
    const int n0  = (blockIdx.x >> 5) << 6;
    for (int u = t; u < 1024; u += 256) {      // Wo rows (bf16, plain copy)
        const int i = u >> 4, cb = (u & 15) << 4;
        *(uint4*)swzPtr((cb < 128) ? sm.s.wl0 : sm.s.wl1, i, cb & 127) =
            *(const uint4*)(Wob + (size_t)(co0 + i) * C_V + (cb >> 1));
    }
    for (int u = t; u < 1024; u += 256) {
        const int i = u >> 4, cb = (u & 15) << 4;
        *(uint4*)swzPtr((cb < 128) ? sm.s.ob0 : sm.s.ob1, i, cb & 127) =
            *(const uint4*)(Ob + ((size_t)((b << 12) + n0 + i) << 7) + (cb >> 1));
    }
    __syncthreads();
    const int arow = (w << 4) + lo;
    const bf16x8 af00 = *(const bf16x8*)swzPtr(sm.s.wl0, arow, hi << 4);
    const bf16x8 af01 = *(const bf16x8*)swzPtr(sm.s.wl0, arow, 64 + (hi << 4));
    const bf16x8 af10 = *(const bf16x8*)swzPtr(sm.s.wl1, arow, hi << 4);
    const bf16x8 af11 = *(const bf16x8*)swzPtr(sm.s.wl1, arow, 64 + (hi << 4));
    f32x4 acc[4];
    #pragma unroll
    for (int ti = 0; ti < 4; ++ti) {
        const int brow = (ti << 4) + lo;
        f32x4 z = (f32x4){0.f, 0.f, 0.f, 0.f};
        z = __builtin_amdgcn_mfma_f32_16x16x32_bf16(af00, *(const bf16x8*)swzPtr(sm.s.ob0, brow, hi << 4), z, 0, 0, 0);
        z = __builtin_amdgcn_mfma_f32_16x16x32_bf16(af01, *(const bf16x8*)swzPtr(sm.s.ob0, brow, 64 + (hi << 4)), z, 0, 0, 0);
        z = __builtin_amdgcn_mfma_f32_16x16x32_bf16(af10, *(const bf16x8*)swzPtr(sm.s.ob1, brow, hi << 4), z, 0, 0, 0);
        acc[ti] = __builtin_amdgcn_mfma_f32_16x16x32_bf16(af11, *(const bf16x8*)swzPtr(sm.s.ob1, brow, 64 + (hi << 4)), z, 0, 0, 0);
    }
    __syncthreads();
    #pragma unroll
    for (int ti = 0; ti < 4; ++ti)
        #pragma unroll
        for (int r = 0; r < 4; ++r) {
            const int co = (w << 4) + (hi << 2) + r;
            const int n  = (ti << 4) + lo;
            sm.tr[(co << 6) + (n ^ (((co >> 2) & 3) << 2))] = acc[ti][r];
        }
    __syncthreads();
    const float g = gamma_p[0];
    for (int u = t; u < 1024; u += 256) {
        const int co = u >> 4, n4 = (u & 15) << 2;
        const float4 av = *(const float4*)&sm.tr[(co << 6) + (n4 ^ (((co >> 2) & 3) << 2))];
        const int o = co0 + co;
        const size_t off = ((size_t)(b * C_IN + o) << 12) + n0 + n4;
        const float4 xv = *(const float4*)(x + off);
        const float bias = bo[o];
        float4 rs;
        rs.x = xv.x + g * (av.x + bias);
        rs.y = xv.y + g * (av.y + bias);
        rs.z = xv.z + g * (av.z + bias);
        rs.w = xv.w + g * (av.w + bias);
        *(float4*)(out + off) = rs;
    }
}

extern "C" void kernel_launch(void* const* d_in, const int* in_sizes, int n_in,
                              void* d_out, int out_size, void* d_ws, size_t ws_size,
                              hipStream_t stream) {
    (void)in_sizes; (void)n_in; (void)out_size; (void)ws_size;
    const float* x  = (const float*)d_in[0];
    const float* Wq = (const float*)d_in[1];
    const float* bq = (const float*)d_in[2];
    const float* Wk = (const float*)d_in[3];
    const float* bk = (const float*)d_in[4];
    const float* Wv = (const float*)d_in[5];
    const float* bv = (const float*)d_in[6];
    const float* Wo = (const float*)d_in[7];
    const float* bo = (const float*)d_in[8];
    const float* gm = (const float*)d_in[9];
    float* out = (float*)d_out;
    // ws layout (bytes), total ~28.7 MB:
    //   [0,16M):  xb bf16 (K0->K1, dead after) ALIASED with po bf16 (512 x 32KB)
    //   [16,18M) Qb | [18,20M) Kf | [20,24M) Vf | [24M,+256K) pl | [+,+4M) Ob
    //   [28.25M,+384K) Wqb 64K | Wkb 64K | Wvb 128K | Wob 128K
    u16* xb = (u16*)d_ws;
    u16* po = (u16*)d_ws;                        // alias: xb dead after K1
    u16* Qb = (u16*)((char*)d_ws + ((size_t)16 << 20));
    u16* Kf = Qb + (size_t)4 * N_SP * C_QK;
    u16* Vf = Kf + (size_t)4 * N_SP * C_QK;
    float* pl = (float*)((char*)d_ws + ((size_t)24 << 20));
    u16* Ob = (u16*)((char*)d_ws + ((size_t)24 << 20) + (256 << 10));
    u16* Wqb = (u16*)((char*)d_ws + ((size_t)24 << 20) + (256 << 10) + ((size_t)4 << 20));
    u16* Wkb = Wqb + 64 * 512;
    u16* Wvb = Wkb + 64 * 512;
    u16* Wob = Wvb + 128 * 512;
    wconv_kernel<<<192, 256, 0, stream>>>(Wq, Wk, Wv, Wo, Wqb, Wkb, Wvb, Wob);
    transpose_kernel<<<2048, 256, 0, stream>>>(x, xb);
    qkv_kernel<<<1024, 256, 0, stream>>>(xb, Wqb, bq, Wkb, bk, Wvb, bv, Qb, Kf, Vf);
    attn_kernel<<<512, 256, 0, stream>>>(Qb, Kf, Vf, po, pl);
    combine_kernel<<<128, 256, 0, stream>>>(po, pl, Ob);
    proj_kernel<<<2048, 256, 0, stream>>>(Ob, Wob, bo, x, gm, out);
}

// Round 17
// 96.298 us; speedup vs baseline: 1.2282x; 1.0838x over previous
//
#include <hip/hip_runtime.h>
#include <cstdint>
#include <cstddef>

#define N_SP 4096
#define C_IN 512
#define C_QK 64
#define C_V  128
#define LOG2E 1.4426950408889634f

typedef unsigned short u16;
typedef __attribute__((ext_vector_type(8))) short bf16x8;
typedef __attribute__((ext_vector_type(4))) float f32x4;
typedef __attribute__((ext_vector_type(16))) float f32x16;

__device__ __forceinline__ u16 f2bf(float f) {
    union { float f; uint32_t u; } x; x.f = f;
    const uint32_t r = x.u + 0x7fffu + ((x.u >> 16) & 1u);
    return (u16)(r >> 16);
}
__device__ __forceinline__ float bf2f(u16 b) {
    union { uint32_t u; float f; } x; x.u = ((uint32_t)b) << 16;
    return x.f;
}

// Swizzled pointer into a 128-byte-row LDS tile: byte ^= (row&7)<<4. (K0/K1/K3 only)
__device__ __forceinline__ void* swzPtr(const void* base, int row, int colByte) {
    return (char*)base + row * 128 + (colByte ^ ((row & 7) << 4));
}

// ---------------- K0: x transpose-convert + (tail blocks) weight conversion ---
// Blocks [0,2048): x[b][c][n] f32 -> xb[b][n][c] bf16.
// Blocks [2048,2240): Wq|Wk|Wv|Wo f32 -> bf16 (one-shot, overlapped with K0).
__global__ __launch_bounds__(256) void transpose_kernel(
    const float* __restrict__ x, u16* __restrict__ xb,
    const float* __restrict__ Wq, const float* __restrict__ Wk,
    const float* __restrict__ Wv, const float* __restrict__ Wo,
    u16* __restrict__ Wqb, u16* __restrict__ Wkb,
    u16* __restrict__ Wvb, u16* __restrict__ Wob)
{
    const int t = threadIdx.x;
    if (blockIdx.x >= 2048) {                  // weight-conversion tail
        const int i = ((blockIdx.x - 2048) << 8) + t;   // quad index
        const float* src; u16* dst; int off;
        if (i < 8192)       { src = Wq; dst = Wqb; off = i; }
        else if (i < 16384) { src = Wk; dst = Wkb; off = i - 8192; }
        else if (i < 32768) { src = Wv; dst = Wvb; off = i - 16384; }
        else                { src = Wo; dst = Wob; off = i - 32768; }
        const float4 v = *(const float4*)(src + ((size_t)off << 2));
        ushort4 h;
        h.x = f2bf(v.x); h.y = f2bf(v.y); h.z = f2bf(v.z); h.w = f2bf(v.w);
        *(ushort4*)(dst + ((size_t)off << 2)) = h;
        return;
    }
    __shared__ u16 ts[64 * 64];
    const int b  = blockIdx.x & 3;
    const int cc = (blockIdx.x >> 2) & 7;
    const int nc = blockIdx.x >> 5;
    const int c0 = cc << 6, n0 = nc << 6;
    const float* xs = x + ((size_t)(b * C_IN + c0) << 12) + n0;
    for (int u = t; u < 1024; u += 256) {
        const int c = u >> 4, nq = (u & 15) << 2;
        const float4 v = *(const float4*)(xs + ((size_t)c << 12) + nq);
        ushort4 h;
        h.x = f2bf(v.x); h.y = f2bf(v.y); h.z = f2bf(v.z); h.w = f2bf(v.w);
        *(ushort4*)((char*)ts + c * 128 + ((nq << 1) ^ (((c >> 3) & 7) << 4))) = h;
    }
    __syncthreads();
    for (int u = t; u < 512; u += 256) {
        const int n = u >> 3, cg = u & 7;
        u16 pk[8];
        #pragma unroll
        for (int j = 0; j < 8; ++j) {
            const int c = (cg << 3) + j;
            pk[j] = *(const u16*)((char*)ts + c * 128 + ((n << 1) ^ (cg << 4)));
        }
        *(ushort4*)(xb + ((size_t)((b << 12) + n0 + n) << 9) + c0 + (cg << 3)) =
            *(ushort4*)&pk[0];
        *(ushort4*)(xb + ((size_t)((b << 12) + n0 + n) << 9) + c0 + (cg << 3) + 4) =
            *(ushort4*)&pk[4];
    }
}

// ---------------- K1: QKV projection, bf16 MFMA (bf16 weights, R14 form) -----
// Q -> Qb[b][n][64] (*log2e). K,V -> fragment-ordered Kf/Vf (see R10).
__global__ __launch_bounds__(256) void qkv_kernel(
    const u16* __restrict__ xb,
    const u16* __restrict__ Wqb, const float* __restrict__ bq,
    const u16* __restrict__ Wkb, const float* __restrict__ bk,
    const u16* __restrict__ Wvb, const float* __restrict__ bv,
    u16* __restrict__ Qb, u16* __restrict__ Kf, u16* __restrict__ Vf)
{
    __shared__ u16 wt[64 * 64];   // W chunk  [o][64 c]
    __shared__ u16 xt[64 * 64];   // xb chunk [n][64 c]
    const int t = threadIdx.x;
    const int l = t & 63, w = t >> 6;
    const int lo = l & 15, hi = l >> 4;
    const int b  = blockIdx.x & 3;
    const int ot = (blockIdx.x >> 2) & 3;
    const int n0 = (blockIdx.x >> 4) << 6;
    const u16* Wbase = (ot == 0) ? Wqb : (ot == 1) ? Wkb : (Wvb + ((ot - 2) << 6) * C_IN);
    f32x4 acc[4];
    #pragma unroll
    for (int ti = 0; ti < 4; ++ti) acc[ti] = (f32x4){0.f, 0.f, 0.f, 0.f};

    for (int cc = 0; cc < 8; ++cc) {
        const int c0 = cc << 6;
        for (int u = t; u < 512; u += 256) {       // W rows (bf16, plain copy)
            const int i = u >> 3, cb = (u & 7) << 4;
            *(uint4*)swzPtr(wt, i, cb) =
                *(const uint4*)(Wbase + (size_t)i * C_IN + c0 + (cb >> 1));
        }
        for (int u = t; u < 512; u += 256) {       // xb rows (already bf16)
            const int i = u >> 3, cb = (u & 7) << 4;
            *(uint4*)swzPtr(xt, i, cb) =
                *(const uint4*)(xb + ((size_t)((b << 12) + n0 + i) << 9) + c0 + (cb >> 1));
        }
        __syncthreads();
        if (ot < 2) {
            const bf16x8 af0 = *(const bf16x8*)swzPtr(xt, (w << 4) + lo, hi << 4);
            const bf16x8 af1 = *(const bf16x8*)swzPtr(xt, (w << 4) + lo, 64 + (hi << 4));
            #pragma unroll
            for (int ti = 0; ti < 4; ++ti) {
                const bf16x8 bf0 = *(const bf16x8*)swzPtr(wt, (ti << 4) + lo, hi << 4);
                const bf16x8 bf1 = *(const bf16x8*)swzPtr(wt, (ti << 4) + lo, 64 + (hi << 4));
                acc[ti] = __builtin_amdgcn_mfma_f32_16x16x32_bf16(af0, bf0, acc[ti], 0, 0, 0);
                acc[ti] = __builtin_amdgcn_mfma_f32_16x16x32_bf16(af1, bf1, acc[ti], 0, 0, 0);
            }
        } else {
            const bf16x8 af0 = *(const bf16x8*)swzPtr(wt, (w << 4) + lo, hi << 4);
            const bf16x8 af1 = *(const bf16x8*)swzPtr(wt, (w << 4) + lo, 64 + (hi << 4));
            #pragma unroll
            for (int ti = 0; ti < 4; ++ti) {
                const bf16x8 bf0 = *(const bf16x8*)swzPtr(xt, (ti << 4) + lo, hi << 4);
                const bf16x8 bf1 = *(const bf16x8*)swzPtr(xt, (ti << 4) + lo, 64 + (hi << 4));
                acc[ti] = __builtin_amdgcn_mfma_f32_16x16x32_bf16(af0, bf0, acc[ti], 0, 0, 0);
                acc[ti] = __builtin_amdgcn_mfma_f32_16x16x32_bf16(af1, bf1, acc[ti], 0, 0, 0);
            }
        }
        __syncthreads();
    }
    const int kt = n0 >> 6;
    if (ot == 0) {        // Q: D row = n_local, col = ch -> Qb[n][64ch], *log2e
        #pragma unroll
        for (int ti = 0; ti < 4; ++ti) {
            const float bias = bq[(ti << 4) + lo];
            #pragma unroll
            for (int r = 0; r < 4; ++r) {
                const int nrow = (w << 4) + (hi << 2) + r;
                Qb[((size_t)((b << 12) + n0 + nrow) << 6) + (ti << 4) + lo] =
                    f2bf((acc[ti][r] + bias) * LOG2E);
            }
        }
    } else if (ot == 1) { // K: fragment order
        #pragma unroll
        for (int ti = 0; ti < 4; ++ti) {
            const int ch = (ti << 4) + lo;
            const float bias = bk[ch];
            #pragma unroll
            for (int r = 0; r < 4; ++r) {
                const int key = (w << 4) + (hi << 2) + r;   // D row = key local
                const int sid = (ti << 1) + (key >> 5);
                const int lpos = (((ch >> 3) & 1) << 5) + (key & 31);
                Kf[(((size_t)((b << 6) + kt) << 3) + sid) * 512 + (lpos << 3) + (ch & 7)] =
                    f2bf(acc[ti][r] + bias);
            }
        }
    } else {              // V: fragment order (D row = cv local, col = n local)
        #pragma unroll
        for (int r = 0; r < 4; ++r) {
            const int cv = ((ot - 2) << 6) + (w << 4) + (hi << 2) + r;
            const float bias = bv[cv];
            #pragma unroll
            for (int ti = 0; ti < 4; ++ti) {
                const int nl = (ti << 4) + lo;              // n local to 64-tile
                const int sv = ((cv >> 5) << 2) + ti;
                const int lpos = (((nl >> 3) & 1) << 5) + (cv & 31);
                Vf[(((size_t)((b << 6) + kt) << 4) + sv) * 512 + (lpos << 3) + (nl & 7)] =
                    f2bf(acc[ti][r] + bias);
            }
        }
    }
}

// ================= K2: barrier-free fragment-direct flash attention ==========
// R16 config + ANTI-PHASE tile rotation: co-resident blocks (c, c+256) start
// 8 tiles apart so the 2 waves per SIMD run MFMA/softmax out of phase.
// Valid because fixed-reference softmax makes KV-tile order commutative.

#define KLOAD(dst, ktl)                                                        \
    {                                                                          \
        const size_t o_ = ((size_t)(((s << 4) + ((ktl) & 15)) << 3)) * 512;    \
        _Pragma("unroll")                                                      \
        for (int i_ = 0; i_ < 8; ++i_)                                         \
            dst[i_] = *(const bf16x8*)(kfb + o_ + i_ * 512);                   \
    }

#define VLOAD(dst, ktl, tjIdx)                                                 \
    {                                                                          \
        const size_t o_ = ((size_t)(((s << 4) + ((ktl) & 15)) << 4) + ((tjIdx) << 2)) * 512; \
        _Pragma("unroll")                                                      \
        for (int i_ = 0; i_ < 4; ++i_)                                         \
            dst[i_] = *(const bf16x8*)(vfb + o_ + i_ * 512);                   \
    }

#define TILE(kt, kfU, kfP)                                                    \
    {                                                                         \
        bf16x8 vA[4], vB[4], vC[4];                                           \
        VLOAD(vA, kt, 0);                                                     \
        f32x16 sa0, sa1;                                                      \
        _Pragma("unroll")                                                     \
        for (int i = 0; i < 16; ++i) { sa0[i] = 0.f; sa1[i] = 0.f; }          \
        __builtin_amdgcn_s_setprio(1);                                        \
        _Pragma("unroll")                                                     \
        for (int ks = 0; ks < 4; ++ks) {                                      \
            sa0 = __builtin_amdgcn_mfma_f32_32x32x16_bf16(kfU[(ks << 1)], qf[ks], sa0, 0, 0, 0);     \
            sa1 = __builtin_amdgcn_mfma_f32_32x32x16_bf16(kfU[(ks << 1) + 1], qf[ks], sa1, 0, 0, 0); \
        }                                                                     \
        __builtin_amdgcn_s_setprio(0);                                        \
        KLOAD(kfP, (kt) + 1);                                                 \
        VLOAD(vB, kt, 1);                                                     \
        float p0[16], p1[16];                                                 \
        _Pragma("unroll")                                                     \
        for (int i = 0; i < 16; ++i) {                                        \
            p0[i] = exp2f(sa0[i]);                                            \
            p1[i] = exp2f(sa1[i]);                                            \
        }                                                                     \
        float sm8[8];                                                         \
        _Pragma("unroll")                                                     \
        for (int i = 0; i < 8; ++i) sm8[i] = (p0[i] + p0[i + 8]) + (p1[i] + p1[i + 8]); \
        _Pragma("unroll")                                                     \
        for (int i = 0; i < 4; ++i) sm8[i] += sm8[i + 4];                     \
        lsum += (sm8[0] + sm8[1]) + (sm8[2] + sm8[3]);                        \
        VLOAD(vC, kt, 2);                                                     \
        uint32_t P2[2][4][2];                                                 \
        _Pragma("unroll")                                                     \
        for (int g = 0; g < 4; ++g) {                                         \
            _Pragma("unroll")                                                 \
            for (int pr = 0; pr < 2; ++pr) {                                  \
                asm("v_cvt_pk_bf16_f32 %0, %1, %2"                            \
                    : "=v"(P2[0][g][pr]) : "v"(p0[4 * g + 2 * pr]), "v"(p0[4 * g + 2 * pr + 1])); \
                asm("v_cvt_pk_bf16_f32 %0, %1, %2"                            \
                    : "=v"(P2[1][g][pr]) : "v"(p1[4 * g + 2 * pr]), "v"(p1[4 * g + 2 * pr + 1])); \
            }                                                                 \
        }                                                                     \
        bf16x8 pf[4];                                                         \
        _Pragma("unroll")                                                     \
        for (int ks = 0; ks < 4; ++ks) {                                      \
            const int iE = ks << 1, iO = iE + 1;                              \
            uint32_t fr[4];                                                   \
            _Pragma("unroll")                                                 \
            for (int pr = 0; pr < 2; ++pr) {                                  \
                uint32_t X = P2[iE >> 2][iE & 3][pr];                         \
                uint32_t Y = P2[iO >> 2][iO & 3][pr];                         \
                asm("v_permlane32_swap_b32 %0, %1" : "+v"(X), "+v"(Y));       \
                fr[pr]     = X;       /* {X_lo | Y_lo} */                     \
                fr[2 + pr] = Y;       /* {X_hi | Y_hi} */                     \
            }                                                                 \
            pf[ks] = *(bf16x8*)fr;                                            \
        }                                                                     \
        __builtin_amdgcn_s_setprio(1);                                        \
        _Pragma("unroll")                                                     \
        for (int ks = 0; ks < 4; ++ks)                                        \
            oacc[0] = __builtin_amdgcn_mfma_f32_32x32x16_bf16(vA[ks], pf[ks], oacc[0], 0, 0, 0); \
        __builtin_amdgcn_s_setprio(0);                                        \
        VLOAD(vA, kt, 3);                                                     \
        __builtin_amdgcn_s_setprio(1);                                        \
        _Pragma("unroll")                                                     \
        for (int ks = 0; ks < 4; ++ks)                                        \
            oacc[1] = __builtin_amdgcn_mfma_f32_32x32x16_bf16(vB[ks], pf[ks], oacc[1], 0, 0, 0); \
        _Pragma("unroll")                                                     \
        for (int ks = 0; ks < 4; ++ks)                                        \
            oacc[2] = __builtin_amdgcn_mfma_f32_32x32x16_bf16(vC[ks], pf[ks], oacc[2], 0, 0, 0); \
        _Pragma("unroll")                                                     \
        for (int ks = 0; ks < 4; ++ks)                                        \
            oacc[3] = __builtin_amdgcn_mfma_f32_32x32x16_bf16(vA[ks], pf[ks], oacc[3], 0, 0, 0); \
        __builtin_amdgcn_s_setprio(0);                                        \
    }

__global__ __launch_bounds__(256, 2) void attn_kernel(
    const u16* __restrict__ Qb, const u16* __restrict__ Kf,
    const u16* __restrict__ Vf, u16* __restrict__ po,
    float* __restrict__ pl)
{
    const int t = threadIdx.x;
    const int l = t & 63, w = t >> 6;          // 4 waves
    const int l31 = l & 31, h = l >> 5;
    const int b = blockIdx.x & 3;
    const int s = (blockIdx.x >> 2) & 3;       // 4-way KV split
    const int qc = blockIdx.x >> 4;
    const int n0 = qc << 7;                    // 128 q per block
    // anti-phase: co-resident blocks (round-robin c, c+256) offset by 8 tiles
    const int kt0 = ((blockIdx.x >> 8) & 1) << 3;

    const u16* qp = Qb + ((size_t)((b << 12) + n0 + (w << 5) + l31) << 6) + (h << 3);
    bf16x8 qf[4];
    #pragma unroll
    for (int ks = 0; ks < 4; ++ks) qf[ks] = *(const bf16x8*)(qp + (ks << 4));

    const u16* kfb = Kf + (((size_t)(b << 6)) << 12) + (l << 3);
    const u16* vfb = Vf + (((size_t)(b << 6)) << 13) + (l << 3);

    float lsum = 0.f;
    f32x16 oacc[4];
    #pragma unroll
    for (int tj = 0; tj < 4; ++tj)
        #pragma unroll
        for (int i = 0; i < 16; ++i) oacc[tj][i] = 0.f;

    bf16x8 kfA[8], kfB[8];
    KLOAD(kfA, kt0);

    for (int kk = 0; kk < 16; kk += 2) {
        TILE(kt0 + kk, kfA, kfB);
        TILE(kt0 + kk + 1, kfB, kfA);
    }

    lsum += __shfl_xor(lsum, 32);
    u16* pod = po + ((size_t)blockIdx.x << 14);   // [128 cv][128 q]
    #pragma unroll
    for (int tj = 0; tj < 4; ++tj)
        #pragma unroll
        for (int r = 0; r < 16; ++r) {
            const int cv = (tj << 5) + (r & 3) + ((r >> 2) << 3) + (h << 2);
            pod[(cv << 7) + (w << 5) + l31] = f2bf(oacc[tj][r]);
        }
    if (h == 0) pl[(blockIdx.x << 7) + (w << 5) + l31] = lsum;
}

// ---------------- K2b: combine (pure sum of 4 splits) -> Ob[b][n][cv] bf16 ---
// Grid 256: one 64-q half (qh) per block.
__global__ __launch_bounds__(256) void combine_kernel(
    const u16* __restrict__ po, const float* __restrict__ pl,
    u16* __restrict__ Ob)
{
    __shared__ float invl[64];
    __shared__ float tr[64][132];
    const int t = threadIdx.x;
    const int b = blockIdx.x & 3;
    const int qh = (blockIdx.x >> 2) & 1;
    const int qc = blockIdx.x >> 3;            // 0..31 (128-q chunks)
    int slot[4];
    #pragma unroll
    for (int s = 0; s < 4; ++s) slot[s] = b + (s << 2) + (qc << 4);
    if (t < 64) {
        const int q = (qh << 6) + t;
        float lg = 0.f;
        #pragma unroll
        for (int s = 0; s < 4; ++s) lg += pl[(slot[s] << 7) + q];
        invl[t] = 1.0f / lg;
    }
    __syncthreads();
    for (int u = t; u < 2048; u += 256) {           // accumulate -> LDS [q][cv]
        const int cv = u >> 4, q4 = (u & 15) << 2;
        const int q = (qh << 6) + q4;
        float a0 = 0.f, a1 = 0.f, a2 = 0.f, a3 = 0.f;
        #pragma unroll
        for (int s = 0; s < 4; ++s) {
            const ushort4 hv =
                *(const ushort4*)(po + ((size_t)slot[s] << 14) + (cv << 7) + q);
            a0 += bf2f(hv.x); a1 += bf2f(hv.y);
            a2 += bf2f(hv.z); a3 += bf2f(hv.w);
        }
        tr[q4 + 0][cv] = a0 * invl[q4 + 0];
        tr[q4 + 1][cv] = a1 * invl[q4 + 1];
        tr[q4 + 2][cv] = a2 * invl[q4 + 2];
        tr[q4 + 3][cv] = a3 * invl[q4 + 3];
    }
    __syncthreads();
    for (int u = t; u < 2048; u += 256) {           // write [n][cv] bf16
        const int q = u >> 5, c4 = (u & 31) << 2;
        const float4 v = *(const float4*)&tr[q][c4];
        ushort4 o;
        o.x = f2bf(v.x); o.y = f2bf(v.y); o.z = f2bf(v.z); o.w = f2bf(v.w);
        const int n = (qc << 7) + (qh << 6) + q;
        *(ushort4*)(Ob + ((size_t)((b << 12) + n) << 7) + c4) = o;
    }
}

// ---------------- K3: output projection + residual, bf16 MFMA (bf16 Wo) ------
__global__ __launch_bounds__(256) void proj_kernel(
    const u16* __restrict__ Ob, const u16* __restrict__ Wob,
    const float* __restrict__ bo, const float* __restrict__ x,
    const float* __restrict__ gamma_p, float* __restrict__ out)
{
    __shared__ union {
        struct { u16 wl0[64 * 64]; u16 wl1[64 * 64]; u16 ob0[64 * 64]; u16 ob1[64 * 64]; } s;
        float tr[64 * 64];
    } sm;
    const int t = threadIdx.x;
    const int l = t & 63, w = t >> 6;
    const int lo = l & 15, hi = l >> 4;
    const int b  = blockIdx.x & 3;
    const int co0 = ((blockIdx.x >> 2) & 7) << 6;
    const int n0  = (blockIdx.x >> 5) << 6;
    for (int u = t; u < 1024; u += 256) {      // Wo rows (bf16, plain copy)
        const int i = u >> 4, cb = (u & 15) << 4;
        *(uint4*)swzPtr((cb < 128) ? sm.s.wl0 : sm.s.wl1, i, cb & 127) =
            *(const uint4*)(Wob + (size_t)(co0 + i) * C_V + (cb >> 1));
    }
    for (int u = t; u < 1024; u += 256) {
        const int i = u >> 4, cb = (u & 15) << 4;
        *(uint4*)swzPtr((cb < 128) ? sm.s.ob0 : sm.s.ob1, i, cb & 127) =
            *(const uint4*)(Ob + ((size_t)((b << 12) + n0 + i) << 7) + (cb >> 1));
    }
    __syncthreads();
    const int arow = (w << 4) + lo;
    const bf16x8 af00 = *(const bf16x8*)swzPtr(sm.s.wl0, arow, hi << 4);
    const bf16x8 af01 = *(const bf16x8*)swzPtr(sm.s.wl0, arow, 64 + (hi << 4));
    const bf16x8 af10 = *(const bf16x8*)swzPtr(sm.s.wl1, arow, hi << 4);
    const bf16x8 af11 = *(const bf16x8*)swzPtr(sm.s.wl1, arow, 64 + (hi << 4));
    f32x4 acc[4];
    #pragma unroll
    for (int ti = 0; ti < 4; ++ti) {
        const int brow = (ti << 4) + lo;
        f32x4 z = (f32x4){0.f, 0.f, 0.f, 0.f};
        z = __builtin_amdgcn_mfma_f32_16x16x32_bf16(af00, *(const bf16x8*)swzPtr(sm.s.ob0, brow, hi << 4), z, 0, 0, 0);
        z = __builtin_amdgcn_mfma_f32_16x16x32_bf16(af01, *(const bf16x8*)swzPtr(sm.s.ob0, brow, 64 + (hi << 4)), z, 0, 0, 0);
        z = __builtin_amdgcn_mfma_f32_16x16x32_bf16(af10, *(const bf16x8*)swzPtr(sm.s.ob1, brow, hi << 4), z, 0, 0, 0);
        acc[ti] = __builtin_amdgcn_mfma_f32_16x16x32_bf16(af11, *(const bf16x8*)swzPtr(sm.s.ob1, brow, 64 + (hi << 4)), z, 0, 0, 0);
    }
    __syncthreads();
    #pragma unroll
    for (int ti = 0; ti < 4; ++ti)
        #pragma unroll
        for (int r = 0; r < 4; ++r) {
            const int co = (w << 4) + (hi << 2) + r;
            const int n  = (ti << 4) + lo;
            sm.tr[(co << 6) + (n ^ (((co >> 2) & 3) << 2))] = acc[ti][r];
        }
    __syncthreads();
    const float g = gamma_p[0];
    for (int u = t; u < 1024; u += 256) {
        const int co = u >> 4, n4 = (u & 15) << 2;
        const float4 av = *(const float4*)&sm.tr[(co << 6) + (n4 ^ (((co >> 2) & 3) << 2))];
        const int o = co0 + co;
        const size_t off = ((size_t)(b * C_IN + o) << 12) + n0 + n4;
        const float4 xv = *(const float4*)(x + off);
        const float bias = bo[o];
        float4 rs;
        rs.x = xv.x + g * (av.x + bias);
        rs.y = xv.y + g * (av.y + bias);
        rs.z = xv.z + g * (av.z + bias);
        rs.w = xv.w + g * (av.w + bias);
        *(float4*)(out + off) = rs;
    }
}

extern "C" void kernel_launch(void* const* d_in, const int* in_sizes, int n_in,
                              void* d_out, int out_size, void* d_ws, size_t ws_size,
                              hipStream_t stream) {
    (void)in_sizes; (void)n_in; (void)out_size; (void)ws_size;
    const float* x  = (const float*)d_in[0];
    const float* Wq = (const float*)d_in[1];
    const float* bq = (const float*)d_in[2];
    const float* Wk = (const float*)d_in[3];
    const float* bk = (const float*)d_in[4];
    const float* Wv = (const float*)d_in[5];
    const float* bv = (const float*)d_in[6];
    const float* Wo = (const float*)d_in[7];
    const float* bo = (const float*)d_in[8];
    const float* gm = (const float*)d_in[9];
    float* out = (float*)d_out;
    // ws layout (bytes), total ~28.7 MB:
    //   [0,16M):  xb bf16 (K0->K1, dead after) ALIASED with po bf16 (512 x 32KB)
    //   [16,18M) Qb | [18,20M) Kf | [20,24M) Vf | [24M,+256K) pl | [+,+4M) Ob
    //   [28.25M,+384K) Wqb 64K | Wkb 64K | Wvb 128K | Wob 128K
    u16* xb = (u16*)d_ws;
    u16* po = (u16*)d_ws;                        // alias: xb dead after K1
    u16* Qb = (u16*)((char*)d_ws + ((size_t)16 << 20));
    u16* Kf = Qb + (size_t)4 * N_SP * C_QK;
    u16* Vf = Kf + (size_t)4 * N_SP * C_QK;
    float* pl = (float*)((char*)d_ws + ((size_t)24 << 20));
    u16* Ob = (u16*)((char*)d_ws + ((size_t)24 << 20) + (256 << 10));
    u16* Wqb = (u16*)((char*)d_ws + ((size_t)24 << 20) + (256 << 10) + ((size_t)4 << 20));
    u16* Wkb = Wqb + 64 * 512;
    u16* Wvb = Wkb + 64 * 512;
    u16* Wob = Wvb + 128 * 512;
    transpose_kernel<<<2240, 256, 0, stream>>>(x, xb, Wq, Wk, Wv, Wo,
                                               Wqb, Wkb, Wvb, Wob);
    qkv_kernel<<<1024, 256, 0, stream>>>(xb, Wqb, bq, Wkb, bk, Wvb, bv, Qb, Kf, Vf);
    attn_kernel<<<512, 256, 0, stream>>>(Qb, Kf, Vf, po, pl);
    combine_kernel<<<256, 256, 0, stream>>>(po, pl, Ob);
    proj_kernel<<<2048, 256, 0, stream>>>(Ob, Wob, bo, x, gm, out);
}

// Round 18
// 95.498 us; speedup vs baseline: 1.2385x; 1.0084x over previous
//
#include <hip/hip_runtime.h>
#include <cstdint>
#include <cstddef>

#define N_SP 4096
#define C_IN 512
#define C_QK 64
#define C_V  128
#define LOG2E 1.4426950408889634f

typedef unsigned short u16;
typedef __attribute__((ext_vector_type(8))) short bf16x8;
typedef __attribute__((ext_vector_type(4))) float f32x4;
typedef __attribute__((ext_vector_type(16))) float f32x16;

__device__ __forceinline__ u16 f2bf(float f) {
    union { float f; uint32_t u; } x; x.f = f;
    const uint32_t r = x.u + 0x7fffu + ((x.u >> 16) & 1u);
    return (u16)(r >> 16);
}
__device__ __forceinline__ float bf2f(u16 b) {
    union { uint32_t u; float f; } x; x.u = ((uint32_t)b) << 16;
    return x.f;
}

// Swizzled pointer into a 128-byte-row LDS tile: byte ^= (row&7)<<4. (K0/K1/K3 only)
__device__ __forceinline__ void* swzPtr(const void* base, int row, int colByte) {
    return (char*)base + row * 128 + (colByte ^ ((row & 7) << 4));
}

// ---------------- K0: x transpose-convert + (tail blocks) weight conversion ---
__global__ __launch_bounds__(256) void transpose_kernel(
    const float* __restrict__ x, u16* __restrict__ xb,
    const float* __restrict__ Wq, const float* __restrict__ Wk,
    const float* __restrict__ Wv, const float* __restrict__ Wo,
    u16* __restrict__ Wqb, u16* __restrict__ Wkb,
    u16* __restrict__ Wvb, u16* __restrict__ Wob)
{
    const int t = threadIdx.x;
    if (blockIdx.x >= 2048) {                  // weight-conversion tail
        const int i = ((blockIdx.x - 2048) << 8) + t;   // quad index
        const float* src; u16* dst; int off;
        if (i < 8192)       { src = Wq; dst = Wqb; off = i; }
        else if (i < 16384) { src = Wk; dst = Wkb; off = i - 8192; }
        else if (i < 32768) { src = Wv; dst = Wvb; off = i - 16384; }
        else                { src = Wo; dst = Wob; off = i - 32768; }
        const float4 v = *(const float4*)(src + ((size_t)off << 2));
        ushort4 h;
        h.x = f2bf(v.x); h.y = f2bf(v.y); h.z = f2bf(v.z); h.w = f2bf(v.w);
        *(ushort4*)(dst + ((size_t)off << 2)) = h;
        return;
    }
    __shared__ u16 ts[64 * 64];
    const int b  = blockIdx.x & 3;
    const int cc = (blockIdx.x >> 2) & 7;
    const int nc = blockIdx.x >> 5;
    const int c0 = cc << 6, n0 = nc << 6;
    const float* xs = x + ((size_t)(b * C_IN + c0) << 12) + n0;
    for (int u = t; u < 1024; u += 256) {
        const int c = u >> 4, nq = (u & 15) << 2;
        const float4 v = *(const float4*)(xs + ((size_t)c << 12) + nq);
        ushort4 h;
        h.x = f2bf(v.x); h.y = f2bf(v.y); h.z = f2bf(v.z); h.w = f2bf(v.w);
        *(ushort4*)((char*)ts + c * 128 + ((nq << 1) ^ (((c >> 3) & 7) << 4))) = h;
    }
    __syncthreads();
    for (int u = t; u < 512; u += 256) {
        const int n = u >> 3, cg = u & 7;
        u16 pk[8];
        #pragma unroll
        for (int j = 0; j < 8; ++j) {
            const int c = (cg << 3) + j;
            pk[j] = *(const u16*)((char*)ts + c * 128 + ((n << 1) ^ (cg << 4)));
        }
        *(ushort4*)(xb + ((size_t)((b << 12) + n0 + n) << 9) + c0 + (cg << 3)) =
            *(ushort4*)&pk[0];
        *(ushort4*)(xb + ((size_t)((b << 12) + n0 + n) << 9) + c0 + (cg << 3) + 4) =
            *(ushort4*)&pk[4];
    }
}

// ---------------- K1: QKV projection, bf16 MFMA (bf16 weights, R14 form) -----
__global__ __launch_bounds__(256) void qkv_kernel(
    const u16* __restrict__ xb,
    const u16* __restrict__ Wqb, const float* __restrict__ bq,
    const u16* __restrict__ Wkb, const float* __restrict__ bk,
    const u16* __restrict__ Wvb, const float* __restrict__ bv,
    u16* __restrict__ Qb, u16* __restrict__ Kf, u16* __restrict__ Vf)
{
    __shared__ u16 wt[64 * 64];   // W chunk  [o][64 c]
    __shared__ u16 xt[64 * 64];   // xb chunk [n][64 c]
    const int t = threadIdx.x;
    const int l = t & 63, w = t >> 6;
    const int lo = l & 15, hi = l >> 4;
    const int b  = blockIdx.x & 3;
    const int ot = (blockIdx.x >> 2) & 3;
    const int n0 = (blockIdx.x >> 4) << 6;
    const u16* Wbase = (ot == 0) ? Wqb : (ot == 1) ? Wkb : (Wvb + ((ot - 2) << 6) * C_IN);
    f32x4 acc[4];
    #pragma unroll
    for (int ti = 0; ti < 4; ++ti) acc[ti] = (f32x4){0.f, 0.f, 0.f, 0.f};

    for (int cc = 0; cc < 8; ++cc) {
        const int c0 = cc << 6;
        for (int u = t; u < 512; u += 256) {       // W rows (bf16, plain copy)
            const int i = u >> 3, cb = (u & 7) << 4;
            *(uint4*)swzPtr(wt, i, cb) =
                *(const uint4*)(Wbase + (size_t)i * C_IN + c0 + (cb >> 1));
        }
        for (int u = t; u < 512; u += 256) {       // xb rows (already bf16)
            const int i = u >> 3, cb = (u & 7) << 4;
            *(uint4*)swzPtr(xt, i, cb) =
                *(const uint4*)(xb + ((size_t)((b << 12) + n0 + i) << 9) + c0 + (cb >> 1));
        }
        __syncthreads();
        if (ot < 2) {
            const bf16x8 af0 = *(const bf16x8*)swzPtr(xt, (w << 4) + lo, hi << 4);
            const bf16x8 af1 = *(const bf16x8*)swzPtr(xt, (w << 4) + lo, 64 + (hi << 4));
            #pragma unroll
            for (int ti = 0; ti < 4; ++ti) {
                const bf16x8 bf0 = *(const bf16x8*)swzPtr(wt, (ti << 4) + lo, hi << 4);
                const bf16x8 bf1 = *(const bf16x8*)swzPtr(wt, (ti << 4) + lo, 64 + (hi << 4));
                acc[ti] = __builtin_amdgcn_mfma_f32_16x16x32_bf16(af0, bf0, acc[ti], 0, 0, 0);
                acc[ti] = __builtin_amdgcn_mfma_f32_16x16x32_bf16(af1, bf1, acc[ti], 0, 0, 0);
            }
        } else {
            const bf16x8 af0 = *(const bf16x8*)swzPtr(wt, (w << 4) + lo, hi << 4);
            const bf16x8 af1 = *(const bf16x8*)swzPtr(wt, (w << 4) + lo, 64 + (hi << 4));
            #pragma unroll
            for (int ti = 0; ti < 4; ++ti) {
                const bf16x8 bf0 = *(const bf16x8*)swzPtr(xt, (ti << 4) + lo, hi << 4);
                const bf16x8 bf1 = *(const bf16x8*)swzPtr(xt, (ti << 4) + lo, 64 + (hi << 4));
                acc[ti] = __builtin_amdgcn_mfma_f32_16x16x32_bf16(af0, bf0, acc[ti], 0, 0, 0);
                acc[ti] = __builtin_amdgcn_mfma_f32_16x16x32_bf16(af1, bf1, acc[ti], 0, 0, 0);
            }
        }
        __syncthreads();
    }
    const int kt = n0 >> 6;
    if (ot == 0) {        // Q: D row = n_local, col = ch -> Qb[n][64ch], *log2e
        #pragma unroll
        for (int ti = 0; ti < 4; ++ti) {
            const float bias = bq[(ti << 4) + lo];
            #pragma unroll
            for (int r = 0; r < 4; ++r) {
                const int nrow = (w << 4) + (hi << 2) + r;
                Qb[((size_t)((b << 12) + n0 + nrow) << 6) + (ti << 4) + lo] =
                    f2bf((acc[ti][r] + bias) * LOG2E);
            }
        }
    } else if (ot == 1) { // K: fragment order
        #pragma unroll
        for (int ti = 0; ti < 4; ++ti) {
            const int ch = (ti << 4) + lo;
            const float bias = bk[ch];
            #pragma unroll
            for (int r = 0; r < 4; ++r) {
                const int key = (w << 4) + (hi << 2) + r;   // D row = key local
                const int sid = (ti << 1) + (key >> 5);
                const int lpos = (((ch >> 3) & 1) << 5) + (key & 31);
                Kf[(((size_t)((b << 6) + kt) << 3) + sid) * 512 + (lpos << 3) + (ch & 7)] =
                    f2bf(acc[ti][r] + bias);
            }
        }
    } else {              // V: fragment order (D row = cv local, col = n local)
        #pragma unroll
        for (int r = 0; r < 4; ++r) {
            const int cv = ((ot - 2) << 6) + (w << 4) + (hi << 2) + r;
            const float bias = bv[cv];
            #pragma unroll
            for (int ti = 0; ti < 4; ++ti) {
                const int nl = (ti << 4) + lo;              // n local to 64-tile
                const int sv = ((cv >> 5) << 2) + ti;
                const int lpos = (((nl >> 3) & 1) << 5) + (cv & 31);
                Vf[(((size_t)((b << 6) + kt) << 4) + sv) * 512 + (lpos << 3) + (nl & 7)] =
                    f2bf(acc[ti][r] + bias);
            }
        }
    }
}

// ================= K2: barrier-free fragment-direct flash attention ==========
// R17 config + LOAD PINNING: compile-time memory fences stop the compiler
// sinking prefetch loads down to their uses (suspected cause of exposed L2
// latency + all prior prefetch nulls). MFMA/VALU still schedule freely
// across the fences (register-only ops). Quadrant 3 gets its own regs (vD)
// and is issued with vC for +150cyc cover.

#define LFENCE asm volatile("" ::: "memory")

#define KLOAD(dst, ktl)                                                        \
    {                                                                          \
        const size_t o_ = ((size_t)(((s << 4) + ((ktl) & 15)) << 3)) * 512;    \
        _Pragma("unroll")                                                      \
        for (int i_ = 0; i_ < 8; ++i_)                                         \
            dst[i_] = *(const bf16x8*)(kfb + o_ + i_ * 512);                   \
    }

#define VLOAD(dst, ktl, tjIdx)                                                 \
    {                                                                          \
        const size_t o_ = ((size_t)(((s << 4) + ((ktl) & 15)) << 4) + ((tjIdx) << 2)) * 512; \
        _Pragma("unroll")                                                      \
        for (int i_ = 0; i_ < 4; ++i_)                                         \
            dst[i_] = *(const bf16x8*)(vfb + o_ + i_ * 512);                   \
    }

#define TILE(kt, kfU, kfP)                                                    \
    {                                                                         \
        bf16x8 vA[4], vB[4], vC[4], vD[4];                                    \
        VLOAD(vA, kt, 0);                                                     \
        LFENCE;                               /* pin vA before S-phase */     \
        f32x16 sa0, sa1;                                                      \
        _Pragma("unroll")                                                     \
        for (int i = 0; i < 16; ++i) { sa0[i] = 0.f; sa1[i] = 0.f; }          \
        __builtin_amdgcn_s_setprio(1);                                        \
        _Pragma("unroll")                                                     \
        for (int ks = 0; ks < 4; ++ks) {                                      \
            sa0 = __builtin_amdgcn_mfma_f32_32x32x16_bf16(kfU[(ks << 1)], qf[ks], sa0, 0, 0, 0);     \
            sa1 = __builtin_amdgcn_mfma_f32_32x32x16_bf16(kfU[(ks << 1) + 1], qf[ks], sa1, 0, 0, 0); \
        }                                                                     \
        __builtin_amdgcn_s_setprio(0);                                        \
        KLOAD(kfP, (kt) + 1);                                                 \
        VLOAD(vB, kt, 1);                                                     \
        LFENCE;                               /* pin K(t+1)+vB before smx */  \
        float p0[16], p1[16];                                                 \
        _Pragma("unroll")                                                     \
        for (int i = 0; i < 16; ++i) {                                        \
            p0[i] = exp2f(sa0[i]);                                            \
            p1[i] = exp2f(sa1[i]);                                            \
        }                                                                     \
        float sm8[8];                                                         \
        _Pragma("unroll")                                                     \
        for (int i = 0; i < 8; ++i) sm8[i] = (p0[i] + p0[i + 8]) + (p1[i] + p1[i + 8]); \
        _Pragma("unroll")                                                     \
        for (int i = 0; i < 4; ++i) sm8[i] += sm8[i + 4];                     \
        lsum += (sm8[0] + sm8[1]) + (sm8[2] + sm8[3]);                        \
        VLOAD(vC, kt, 2);                                                     \
        VLOAD(vD, kt, 3);                                                     \
        LFENCE;                               /* pin vC+vD before pack */     \
        uint32_t P2[2][4][2];                                                 \
        _Pragma("unroll")                                                     \
        for (int g = 0; g < 4; ++g) {                                         \
            _Pragma("unroll")                                                 \
            for (int pr = 0; pr < 2; ++pr) {                                  \
                asm("v_cvt_pk_bf16_f32 %0, %1, %2"                            \
                    : "=v"(P2[0][g][pr]) : "v"(p0[4 * g + 2 * pr]), "v"(p0[4 * g + 2 * pr + 1])); \
                asm("v_cvt_pk_bf16_f32 %0, %1, %2"                            \
                    : "=v"(P2[1][g][pr]) : "v"(p1[4 * g + 2 * pr]), "v"(p1[4 * g + 2 * pr + 1])); \
            }                                                                 \
        }                                                                     \
        bf16x8 pf[4];                                                         \
        _Pragma("unroll")                                                     \
        for (int ks = 0; ks < 4; ++ks) {                                      \
            const int iE = ks << 1, iO = iE + 1;                              \
            uint32_t fr[4];                                                   \
            _Pragma("unroll")                                                 \
            for (int pr = 0; pr < 2; ++pr) {                                  \
                uint32_t X = P2[iE >> 2][iE & 3][pr];                         \
                uint32_t Y = P2[iO >> 2][iO & 3][pr];                         \
                asm("v_permlane32_swap_b32 %0, %1" : "+v"(X), "+v"(Y));       \
                fr[pr]     = X;       /* {X_lo | Y_lo} */                     \
                fr[2 + pr] = Y;       /* {X_hi | Y_hi} */                     \
            }                                                                 \
            pf[ks] = *(bf16x8*)fr;                                            \
        }                                                                     \
        __builtin_amdgcn_s_setprio(1);                                        \
        _Pragma("unroll")                                                     \
        for (int ks = 0; ks < 4; ++ks)                                        \
            oacc[0] = __builtin_amdgcn_mfma_f32_32x32x16_bf16(vA[ks], pf[ks], oacc[0], 0, 0, 0); \
        _Pragma("unroll")                                                     \
        for (int ks = 0; ks < 4; ++ks)                                        \
            oacc[1] = __builtin_amdgcn_mfma_f32_32x32x16_bf16(vB[ks], pf[ks], oacc[1], 0, 0, 0); \
        _Pragma("unroll")                                                     \
        for (int ks = 0; ks < 4; ++ks)                                        \
            oacc[2] = __builtin_amdgcn_mfma_f32_32x32x16_bf16(vC[ks], pf[ks], oacc[2], 0, 0, 0); \
        _Pragma("unroll")                                                     \
        for (int ks = 0; ks < 4; ++ks)                                        \
            oacc[3] = __builtin_amdgcn_mfma_f32_32x32x16_bf16(vD[ks], pf[ks], oacc[3], 0, 0, 0); \
        __builtin_amdgcn_s_setprio(0);                                        \
    }

__global__ __launch_bounds__(256, 2) void attn_kernel(
    const u16* __restrict__ Qb, const u16* __restrict__ Kf,
    const u16* __restrict__ Vf, u16* __restrict__ po,
    float* __restrict__ pl)
{
    const int t = threadIdx.x;
    const int l = t & 63, w = t >> 6;          // 4 waves
    const int l31 = l & 31, h = l >> 5;
    const int b = blockIdx.x & 3;
    const int s = (blockIdx.x >> 2) & 3;       // 4-way KV split
    const int qc = blockIdx.x >> 4;
    const int n0 = qc << 7;                    // 128 q per block
    const int kt0 = ((blockIdx.x >> 8) & 1) << 3;   // anti-phase rotation

    const u16* qp = Qb + ((size_t)((b << 12) + n0 + (w << 5) + l31) << 6) + (h << 3);
    bf16x8 qf[4];
    #pragma unroll
    for (int ks = 0; ks < 4; ++ks) qf[ks] = *(const bf16x8*)(qp + (ks << 4));

    const u16* kfb = Kf + (((size_t)(b << 6)) << 12) + (l << 3);
    const u16* vfb = Vf + (((size_t)(b << 6)) << 13) + (l << 3);

    float lsum = 0.f;
    f32x16 oacc[4];
    #pragma unroll
    for (int tj = 0; tj < 4; ++tj)
        #pragma unroll
        for (int i = 0; i < 16; ++i) oacc[tj][i] = 0.f;

    bf16x8 kfA[8], kfB[8];
    KLOAD(kfA, kt0);
    LFENCE;

    for (int kk = 0; kk < 16; kk += 2) {
        TILE(kt0 + kk, kfA, kfB);
        TILE(kt0 + kk + 1, kfB, kfA);
    }

    lsum += __shfl_xor(lsum, 32);
    u16* pod = po + ((size_t)blockIdx.x << 14);   // [128 cv][128 q]
    #pragma unroll
    for (int tj = 0; tj < 4; ++tj)
        #pragma unroll
        for (int r = 0; r < 16; ++r) {
            const int cv = (tj << 5) + (r & 3) + ((r >> 2) << 3) + (h << 2);
            pod[(cv << 7) + (w << 5) + l31] = f2bf(oacc[tj][r]);
        }
    if (h == 0) pl[(blockIdx.x << 7) + (w << 5) + l31] = lsum;
}

// ---------------- K2b: combine (pure sum of 4 splits) -> Ob[b][n][cv] bf16 ---
__global__ __launch_bounds__(256) void combine_kernel(
    const u16* __restrict__ po, const float* __restrict__ pl,
    u16* __restrict__ Ob)
{
    __shared__ float invl[64];
    __shared__ float tr[64][132];
    const int t = threadIdx.x;
    const int b = blockIdx.x & 3;
    const int qh = (blockIdx.x >> 2) & 1;
    const int qc = blockIdx.x >> 3;            // 0..31 (128-q chunks)
    int slot[4];
    #pragma unroll
    for (int s = 0; s < 4; ++s) slot[s] = b + (s << 2) + (qc << 4);
    if (t < 64) {
        const int q = (qh << 6) + t;
        float lg = 0.f;
        #pragma unroll
        for (int s = 0; s < 4; ++s) lg += pl[(slot[s] << 7) + q];
        invl[t] = 1.0f / lg;
    }
    __syncthreads();
    for (int u = t; u < 2048; u += 256) {           // accumulate -> LDS [q][cv]
        const int cv = u >> 4, q4 = (u & 15) << 2;
        const int q = (qh << 6) + q4;
        float a0 = 0.f, a1 = 0.f, a2 = 0.f, a3 = 0.f;
        #pragma unroll
        for (int s = 0; s < 4; ++s) {
            const ushort4 hv =
                *(const ushort4*)(po + ((size_t)slot[s] << 14) + (cv << 7) + q);
            a0 += bf2f(hv.x); a1 += bf2f(hv.y);
            a2 += bf2f(hv.z); a3 += bf2f(hv.w);
        }
        tr[q4 + 0][cv] = a0 * invl[q4 + 0];
        tr[q4 + 1][cv] = a1 * invl[q4 + 1];
        tr[q4 + 2][cv] = a2 * invl[q4 + 2];
        tr[q4 + 3][cv] = a3 * invl[q4 + 3];
    }
    __syncthreads();
    for (int u = t; u < 2048; u += 256) {           // write [n][cv] bf16
        const int q = u >> 5, c4 = (u & 31) << 2;
        const float4 v = *(const float4*)&tr[q][c4];
        ushort4 o;
        o.x = f2bf(v.x); o.y = f2bf(v.y); o.z = f2bf(v.z); o.w = f2bf(v.w);
        const int n = (qc << 7) + (qh << 6) + q;
        *(ushort4*)(Ob + ((size_t)((b << 12) + n) << 7) + c4) = o;
    }
}

// ---------------- K3: output projection + residual, bf16 MFMA (bf16 Wo) ------
__global__ __launch_bounds__(256) void proj_kernel(
    const u16* __restrict__ Ob, const u16* __restrict__ Wob,
    const float* __restrict__ bo, const float* __restrict__ x,
    const float* __restrict__ gamma_p, float* __restrict__ out)
{
    __shared__ union {
        struct { u16 wl0[64 * 64]; u16 wl1[64 * 64]; u16 ob0[64 * 64]; u16 ob1[64 * 64]; } s;
        float tr[64 * 64];
    } sm;
    const int t = threadIdx.x;
    const int l = t & 63, w = t >> 6;
    const int lo = l & 15, hi = l >> 4;
    const int b  = blockIdx.x & 3;
    const int co0 = ((blockIdx.x >> 2) & 7) << 6;
    const int n0  = (blockIdx.x >> 5) << 6;
    for (int u = t; u < 1024; u += 256) {      // Wo rows (bf16, plain copy)
        const int i = u >> 4, cb = (u & 15) << 4;
        *(uint4*)swzPtr((cb < 128) ? sm.s.wl0 : sm.s.wl1, i, cb & 127) =
            *(const uint4*)(Wob + (size_t)(co0 + i) * C_V + (cb >> 1));
    }
    for (int u = t; u < 1024; u += 256) {
        const int i = u >> 4, cb = (u & 15) << 4;
        *(uint4*)swzPtr((cb < 128) ? sm.s.ob0 : sm.s.ob1, i, cb & 127) =
            *(const uint4*)(Ob + ((size_t)((b << 12) + n0 + i) << 7) + (cb >> 1));
    }
    __syncthreads();
    const int arow = (w << 4) + lo;
    const bf16x8 af00 = *(const bf16x8*)swzPtr(sm.s.wl0, arow, hi << 4);
    const bf16x8 af01 = *(const bf16x8*)swzPtr(sm.s.wl0, arow, 64 + (hi << 4));
    const bf16x8 af10 = *(const bf16x8*)swzPtr(sm.s.wl1, arow, hi << 4);
    const bf16x8 af11 = *(const bf16x8*)swzPtr(sm.s.wl1, arow, 64 + (hi << 4));
    f32x4 acc[4];
    #pragma unroll
    for (int ti = 0; ti < 4; ++ti) {
        const int brow = (ti << 4) + lo;
        f32x4 z = (f32x4){0.f, 0.f, 0.f, 0.f};
        z = __builtin_amdgcn_mfma_f32_16x16x32_bf16(af00, *(const bf16x8*)swzPtr(sm.s.ob0, brow, hi << 4), z, 0, 0, 0);
        z = __builtin_amdgcn_mfma_f32_16x16x32_bf16(af01, *(const bf16x8*)swzPtr(sm.s.ob0, brow, 64 + (hi << 4)), z, 0, 0, 0);
        z = __builtin_amdgcn_mfma_f32_16x16x32_bf16(af10, *(const bf16x8*)swzPtr(sm.s.ob1, brow, hi << 4), z, 0, 0, 0);
        acc[ti] = __builtin_amdgcn_mfma_f32_16x16x32_bf16(af11, *(const bf16x8*)swzPtr(sm.s.ob1, brow, 64 + (hi << 4)), z, 0, 0, 0);
    }
    __syncthreads();
    #pragma unroll
    for (int ti = 0; ti < 4; ++ti)
        #pragma unroll
        for (int r = 0; r < 4; ++r) {
            const int co = (w << 4) + (hi << 2) + r;
            const int n  = (ti << 4) + lo;
            sm.tr[(co << 6) + (n ^ (((co >> 2) & 3) << 2))] = acc[ti][r];
        }
    __syncthreads();
    const float g = gamma_p[0];
    for (int u = t; u < 1024; u += 256) {
        const int co = u >> 4, n4 = (u & 15) << 2;
        const float4 av = *(const float4*)&sm.tr[(co << 6) + (n4 ^ (((co >> 2) & 3) << 2))];
        const int o = co0 + co;
        const size_t off = ((size_t)(b * C_IN + o) << 12) + n0 + n4;
        const float4 xv = *(const float4*)(x + off);
        const float bias = bo[o];
        float4 rs;
        rs.x = xv.x + g * (av.x + bias);
        rs.y = xv.y + g * (av.y + bias);
        rs.z = xv.z + g * (av.z + bias);
        rs.w = xv.w + g * (av.w + bias);
        *(float4*)(out + off) = rs;
    }
}

extern "C" void kernel_launch(void* const* d_in, const int* in_sizes, int n_in,
                              void* d_out, int out_size, void* d_ws, size_t ws_size,
                              hipStream_t stream) {
    (void)in_sizes; (void)n_in; (void)out_size; (void)ws_size;
    const float* x  = (const float*)d_in[0];
    const float* Wq = (const float*)d_in[1];
    const float* bq = (const float*)d_in[2];
    const float* Wk = (const float*)d_in[3];
    const float* bk = (const float*)d_in[4];
    const float* Wv = (const float*)d_in[5];
    const float* bv = (const float*)d_in[6];
    const float* Wo = (const float*)d_in[7];
    const float* bo = (const float*)d_in[8];
    const float* gm = (const float*)d_in[9];
    float* out = (float*)d_out;
    // ws layout (bytes), total ~28.7 MB:
    //   [0,16M):  xb bf16 (K0->K1, dead after) ALIASED with po bf16 (512 x 32KB)
    //   [16,18M) Qb | [18,20M) Kf | [20,24M) Vf | [24M,+256K) pl | [+,+4M) Ob
    //   [28.25M,+384K) Wqb 64K | Wkb 64K | Wvb 128K | Wob 128K
    u16* xb = (u16*)d_ws;
    u16* po = (u16*)d_ws;                        // alias: xb dead after K1
    u16* Qb = (u16*)((char*)d_ws + ((size_t)16 << 20));
    u16* Kf = Qb + (size_t)4 * N_SP * C_QK;
    u16* Vf = Kf + (size_t)4 * N_SP * C_QK;
    float* pl = (float*)((char*)d_ws + ((size_t)24 << 20));
    u16* Ob = (u16*)((char*)d_ws + ((size_t)24 << 20) + (256 << 10));
    u16* Wqb = (u16*)((char*)d_ws + ((size_t)24 << 20) + (256 << 10) + ((size_t)4 << 20));
    u16* Wkb = Wqb + 64 * 512;
    u16* Wvb = Wkb + 64 * 512;
    u16* Wob = Wvb + 128 * 512;
    transpose_kernel<<<2240, 256, 0, stream>>>(x, xb, Wq, Wk, Wv, Wo,
                                               Wqb, Wkb, Wvb, Wob);
    qkv_kernel<<<1024, 256, 0, stream>>>(xb, Wqb, bq, Wkb, bk, Wvb, bv, Qb, Kf, Vf);
    attn_kernel<<<512, 256, 0, stream>>>(Qb, Kf, Vf, po, pl);
    combine_kernel<<<256, 256, 0, stream>>>(po, pl, Ob);
    proj_kernel<<<2048, 256, 0, stream>>>(Ob, Wob, bo, x, gm, out);
}